// Round 10
// baseline (697.963 us; speedup 1.0000x reference)
//
#include <hip/hip_runtime.h>
#include <math.h>

// Problem constants
#define BB 4
#define CCH 128
#define LL 4096
#define LOG2E 1.44269504088896340736f

__device__ __forceinline__ float exp2fast(float x) {
    float r; asm("v_exp_f32 %0, %1" : "=v"(r) : "v"(x)); return r;
}
__device__ __forceinline__ float softplusf(float x) {
    return x > 20.f ? x : log1pf(expf(x));
}
__device__ __forceinline__ float sigmf(float x) {
    return 1.f / (1.f + expf(-x));
}

// direction map: seq position -> source index in row-major (h*64+w) layout.
// dirmap(k,.) is an involution for every k.
__device__ __forceinline__ int dirmap(int k, int l) {
    if (k == 0) return l;
    if (k == 1) return ((l & 63) << 6) | (l >> 6);
    if (k == 2) return LL - 1 - l;
    int j = LL - 1 - l; return ((j & 63) << 6) | (j >> 6);
}

// ---------------- prep: A2[k,d,n] = -exp(A_log[k*64+d,n]) * log2(e) ----------------
__global__ void k_prepA(const float* __restrict__ Alog2, const float* __restrict__ Alog4,
                        float* __restrict__ A2_2, float* __restrict__ A2_4) {
    int i = blockIdx.x * 256 + threadIdx.x;
    if (i < 4 * 64 * 8)  A2_2[i] = -expf(Alog2[i]) * LOG2E;
    if (i < 4 * 64 * 24) A2_4[i] = -expf(Alog4[i]) * LOG2E;
}

// ---------------- x13 = x1 + x3 ; x42 = x4 + x2 (each (B,32,L)) ----------------
__global__ void k_addgroups(const float* __restrict__ x, float* __restrict__ x13, float* __restrict__ x42) {
    int i = blockIdx.x * 256 + threadIdx.x;        // over B*32*L
    int l = i & (LL - 1); int c = (i >> 12) & 31; int b = i >> 17;
    const float* xb = x + (size_t)b * CCH * LL;
    x13[i] = xb[(64 + c) * LL + l] + xb[(0 + c) * LL + l];
    x42[i] = xb[(96 + c) * LL + l] + xb[(32 + c) * LL + l];
}

// ---------------- channel means over L ----------------
__global__ void k_pool(const float* __restrict__ src, float* __restrict__ dst) {
    int bc = blockIdx.x;
    const float* p = src + (size_t)bc * LL;
    float s = 0.f;
    for (int i = threadIdx.x; i < LL; i += 256) s += p[i];
    for (int m = 32; m >= 1; m >>= 1) s += __shfl_xor(s, m, 64);
    __shared__ float ws[4];
    if ((threadIdx.x & 63) == 0) ws[threadIdx.x >> 6] = s;
    __syncthreads();
    if (threadIdx.x == 0) dst[bc] = (ws[0] + ws[1] + ws[2] + ws[3]) * (1.f / LL);
}

// ---------------- conv1 (3x3 pad1 +BN+ReLU), LDS-staged ----------------
__global__ __launch_bounds__(256) void k_conv1L(const float* __restrict__ x,
                        const float* __restrict__ w1,
                        const float* __restrict__ g, const float* __restrict__ bt,
                        const float* __restrict__ m, const float* __restrict__ v,
                        float* __restrict__ out1) {
    __shared__ float t[32][3][66];
    int b = blockIdx.x >> 6, h = blockIdx.x & 63;
    int lane = threadIdx.x & 63, wv = threadIdx.x >> 6;
    const float* xb = x + (size_t)b * CCH * LL;
    for (int i = threadIdx.x; i < 192; i += 256) {      // 32ci*3r*2 halo cols
        int ci = i / 6, rem = i % 6;
        t[ci][rem >> 1][(rem & 1) ? 65 : 0] = 0.f;
    }
    for (int i = threadIdx.x; i < 6144; i += 256) {     // interior, coalesced
        int ci = i / 192, rem = i % 192;
        int r = rem >> 6, col = rem & 63;
        int hh = h + r - 1;
        t[ci][r][col + 1] = ((unsigned)hh < 64u) ? xb[ci * LL + hh * 64 + col] : 0.f;
    }
    __syncthreads();
    float a[8];
    #pragma unroll
    for (int j = 0; j < 8; j++) a[j] = 0.f;
    for (int ci = 0; ci < 32; ci++) {
        #pragma unroll
        for (int r = 0; r < 3; r++) {
            float v0 = t[ci][r][lane];
            float v1 = t[ci][r][lane + 1];
            float v2 = t[ci][r][lane + 2];
            #pragma unroll
            for (int j = 0; j < 8; j++) {
                const float* wp = w1 + ((wv * 8 + j) * 32 + ci) * 9 + r * 3;
                a[j] = fmaf(wp[0], v0, fmaf(wp[1], v1, fmaf(wp[2], v2, a[j])));
            }
        }
    }
    #pragma unroll
    for (int j = 0; j < 8; j++) {
        int co = wv * 8 + j;
        float sc = g[co] * rsqrtf(v[co] + 1e-5f);
        float bs = bt[co] - m[co] * sc;
        out1[(size_t)(b * 32 + co) * LL + h * 64 + lane] = fmaxf(fmaf(a[j], sc, bs), 0.f);
    }
}

// ---------------- conv3 (3x3 dil12 pad12 + ReLU), LDS-staged, input x13 ----------------
__global__ __launch_bounds__(256) void k_conv3L(const float* __restrict__ x13,
                        const float* __restrict__ w3, float* __restrict__ out3) {
    __shared__ float t[32][3][88];                      // halo 12 each side
    int b = blockIdx.x >> 6, h = blockIdx.x & 63;
    int lane = threadIdx.x & 63, wv = threadIdx.x >> 6;
    const float* xb = x13 + (size_t)b * 32 * LL;
    for (int i = threadIdx.x; i < 2304; i += 256) {     // 32*3*24 halo cols
        int ci = i / 72, rem = i % 72;
        int r = rem / 24, cz = rem % 24;
        t[ci][r][(cz < 12) ? cz : (cz + 64)] = 0.f;
    }
    for (int i = threadIdx.x; i < 6144; i += 256) {     // interior, coalesced
        int ci = i / 192, rem = i % 192;
        int r = rem >> 6, col = rem & 63;
        int hh = h + (r - 1) * 12;
        t[ci][r][col + 12] = ((unsigned)hh < 64u) ? xb[ci * LL + hh * 64 + col] : 0.f;
    }
    __syncthreads();
    float a[8];
    #pragma unroll
    for (int j = 0; j < 8; j++) a[j] = 0.f;
    for (int ci = 0; ci < 32; ci++) {
        #pragma unroll
        for (int r = 0; r < 3; r++) {
            float v0 = t[ci][r][lane];
            float v1 = t[ci][r][lane + 12];
            float v2 = t[ci][r][lane + 24];
            #pragma unroll
            for (int j = 0; j < 8; j++) {
                const float* wp = w3 + ((wv * 8 + j) * 32 + ci) * 9 + r * 3;
                a[j] = fmaf(wp[0], v0, fmaf(wp[1], v1, fmaf(wp[2], v2, a[j])));
            }
        }
    }
    #pragma unroll
    for (int j = 0; j < 8; j++) {
        int co = wv * 8 + j;
        out3[(size_t)(b * 32 + co) * LL + h * 64 + lane] = fmaxf(a[j], 0.f);
    }
}

// ---------------- S1: in-proj 128x32 -> xiT (B,L,64), zT (B,L,64) ----------------
__global__ __launch_bounds__(256) void k_s1(const float* __restrict__ src, int bstride, int coff,
                     const float* __restrict__ in_w,
                     float* __restrict__ xiT, float* __restrict__ zT) {
    int blk = blockIdx.x;                           // B * (L/64)
    int l0 = (blk & 63) * 64; int b = blk >> 6;
    int lq = threadIdx.x & 63; int esub = threadIdx.x >> 6;
    __shared__ float xin[32][64];
    __shared__ float xit[64][65];
    __shared__ float zt[64][65];
    for (int i = threadIdx.x; i < 32 * 64; i += 256) {
        int c = i >> 6, q = i & 63;
        xin[c][q] = src[(size_t)b * bstride + (size_t)(coff + c) * LL + l0 + q];
    }
    __syncthreads();
    for (int it = 0; it < 32; it++) {
        int e = esub * 32 + it;
        const float* wr = in_w + e * 32;
        float acc = 0.f;
        #pragma unroll 8
        for (int c = 0; c < 32; c++) acc += wr[c] * xin[c][lq];
        if (e < 64) xit[lq][e] = acc;
        else        zt[lq][e - 64] = acc;
    }
    __syncthreads();
    for (int i = threadIdx.x; i < 64 * 64; i += 256) {
        int q = i >> 6, d = i & 63;
        size_t st = ((size_t)b * LL + l0 + q) * 64 + d;
        xiT[st] = xit[q][d];
        zT[st]  = zt[q][d];
    }
}

// ---------------- S2: depthwise KxK + bias + SiLU -> xcT (B,L,64) ----------------
template<int K>
__global__ __launch_bounds__(256) void k_s2(const float* __restrict__ xiT, const float* __restrict__ cw,
                     const float* __restrict__ cb, float* __restrict__ xcT) {
    __shared__ float wl[64 * K * K];
    for (int j = threadIdx.x; j < 64 * K * K; j += 256) wl[j] = cw[j];
    __syncthreads();
    int i = blockIdx.x * 256 + threadIdx.x;         // B*L*64, d inner
    int d = i & 63; int l = (i >> 6) & (LL - 1); int b = i >> 18;
    int h = l >> 6, wx = l & 63;
    const int P = (K - 1) / 2;
    const float* xb = xiT + (size_t)b * LL * 64;
    const float* wp = wl + d * K * K;
    float acc = cb[d];
    #pragma unroll
    for (int kh = 0; kh < K; kh++) {
        int hh = h + kh - P; if ((unsigned)hh >= 64u) continue;
        #pragma unroll
        for (int kw = 0; kw < K; kw++) {
            int w2 = wx + kw - P; if ((unsigned)w2 >= 64u) continue;
            acc += wp[kh * K + kw] * xb[(size_t)(hh * 64 + w2) * 64 + d];
        }
    }
    xcT[i] = acc / (1.f + expf(-acc));              // SiLU
}

// ---------------- S3: x_dbl proj -> r01 (bk,l,2), Bs (bk,l,N), Cs (bk,l,N) ----------------
template<int N>
__global__ __launch_bounds__(256) void k_s3(const float* __restrict__ xcT, const float* __restrict__ xp_w,
                     float* __restrict__ r01, float* __restrict__ Bsb, float* __restrict__ Csb) {
    const int CD = 2 + 2 * N;
    int blk = blockIdx.x;                           // b*4*256 tiles of 16
    int lt = blk & 255; int k = (blk >> 8) & 3; int b = blk >> 10;
    int l0 = lt * 16; int bk = b * 4 + k;
    __shared__ float xt[64][17];
    __shared__ float xp[CD * 64];
    __shared__ float accs[CD][16];
    for (int i = threadIdx.x; i < 64 * 16; i += 256) {
        int dd = i & 63, lq = i >> 6;
        xt[dd][lq] = xcT[((size_t)b * LL + dirmap(k, l0 + lq)) * 64 + dd];
    }
    for (int i = threadIdx.x; i < CD * 64; i += 256) xp[i] = xp_w[(size_t)k * CD * 64 + i];
    __syncthreads();
    for (int o = threadIdx.x; o < CD * 16; o += 256) {
        int cc = o >> 4, lq = o & 15;
        const float* wr = &xp[cc * 64];
        float acc = 0.f;
        #pragma unroll 8
        for (int dd = 0; dd < 64; dd++) acc += wr[dd] * xt[dd][lq];
        accs[cc][lq] = acc;
    }
    __syncthreads();
    for (int i = threadIdx.x; i < 32; i += 256) {
        int lq = i >> 1, j = i & 1;
        r01[((size_t)bk * LL + l0 + lq) * 2 + j] = accs[j][lq];
    }
    for (int i = threadIdx.x; i < 16 * N; i += 256) {
        int lq = i / N, n = i - lq * N;
        Bsb[((size_t)bk * LL + l0 + lq) * N + n] = accs[2 + n][lq];
        Csb[((size_t)bk * LL + l0 + lq) * N + n] = accs[2 + N + n][lq];
    }
}

// ---------------- scan phase A: lane = d; chunk of 32 steps per wave ----------------
// dt prefetch: double-buffered 8-step tiles break the rp->dt->exp serial chain
// (round-9 profile: VALUBusy 38%, waves 81% stalled on that load chain).
// Accumulation order over (t,n) unchanged -> bit-identical results.
template<int N>
__global__ __launch_bounds__(256) void k_scanA(
    const float* __restrict__ r01, const float* __restrict__ Bs,
    const float* __restrict__ xcT, const float* __restrict__ A2,
    const float* __restrict__ dtw, const float* __restrict__ dtb,
    float* __restrict__ Pp, float* __restrict__ Hl) {
    int bk = blockIdx.x >> 5; int c = (blockIdx.x & 31) * 4 + (threadIdx.x >> 6);
    int d = threadIdx.x & 63;
    int k = bk & 3, b = bk >> 2;
    float w0 = dtw[(k * 64 + d) * 2], w1 = dtw[(k * 64 + d) * 2 + 1], bd = dtb[k * 64 + d];
    float a2[N], h[N], P[N];
    #pragma unroll
    for (int n = 0; n < N; n++) { a2[n] = A2[(k * 64 + d) * N + n]; h[n] = 0.f; P[n] = 1.f; }
    int l0 = c * 32;
    const float2* rp  = (const float2*)(r01 + (size_t)bk * LL * 2) + l0;
    const float4* Bp4 = (const float4*)(Bs + (size_t)bk * LL * N);
    const float*  xb  = xcT + (size_t)b * LL * 64;
    float2 rv[8];
    #pragma unroll
    for (int j = 0; j < 8; j++) rv[j] = rp[j];
    for (int tile = 0; tile < 4; tile++) {
        float2 rvn[8];
        if (tile < 3) {
            #pragma unroll
            for (int j = 0; j < 8; j++) rvn[j] = rp[(tile + 1) * 8 + j];
        }
        float dts[8];
        #pragma unroll
        for (int j = 0; j < 8; j++)
            dts[j] = softplusf(fmaf(rv[j].x, w0, fmaf(rv[j].y, w1, bd)));
        #pragma unroll
        for (int j = 0; j < 8; j++) {
            int l = l0 + tile * 8 + j;
            float dt = dts[j];
            float du = dt * xb[(size_t)dirmap(k, l) * 64 + d];
            #pragma unroll
            for (int n4 = 0; n4 < N / 4; n4++) {
                float4 bv = Bp4[(size_t)l * (N / 4) + n4];
                float bvs[4] = {bv.x, bv.y, bv.z, bv.w};
                #pragma unroll
                for (int jj = 0; jj < 4; jj++) {
                    int n = n4 * 4 + jj;
                    float a = exp2fast(dt * a2[n]);
                    P[n] *= a;
                    h[n] = fmaf(a, h[n], du * bvs[jj]);
                }
            }
        }
        #pragma unroll
        for (int j = 0; j < 8; j++) rv[j] = rvn[j];
    }
    size_t o = (size_t)(bk * 128 + c) * N * 64 + d;
    #pragma unroll
    for (int n = 0; n < N; n++) { Pp[o + n * 64] = P[n]; Hl[o + n * 64] = h[n]; }
}

// ---------------- scan phase B: sequential carry compose; Hin in-place over Hl ----------------
template<int N>
__global__ void k_scanB(const float* __restrict__ Pp, float* __restrict__ Hl) {
    int g = blockIdx.x * 256 + threadIdx.x;         // 16 * N * 64
    if (g >= 16 * N * 64) return;
    int d = g & 63; int n = (g >> 6) % N; int bk = g / (N * 64);
    float acc = 0.f;
    #pragma unroll 4
    for (int c = 0; c < 128; c++) {
        size_t o = (size_t)(bk * 128 + c) * N * 64 + n * 64 + d;
        float Pv = Pp[o], Hv = Hl[o];
        Hl[o] = acc;                                // exclusive prefix = h_in for chunk c
        acc = fmaf(Pv, acc, Hv);
    }
}

// ---------------- scan phase C: replay from h_in, emit y directly in spatial order ----------------
template<int N>
__global__ __launch_bounds__(256) void k_scanC(
    const float* __restrict__ r01, const float* __restrict__ Bs,
    const float* __restrict__ Cs, const float* __restrict__ xcT,
    const float* __restrict__ A2, const float* __restrict__ dtw,
    const float* __restrict__ dtb, const float* __restrict__ Hin,
    float* __restrict__ yrT) {
    int bk = blockIdx.x >> 5; int c = (blockIdx.x & 31) * 4 + (threadIdx.x >> 6);
    int d = threadIdx.x & 63;
    int k = bk & 3, b = bk >> 2;
    float w0 = dtw[(k * 64 + d) * 2], w1 = dtw[(k * 64 + d) * 2 + 1], bd = dtb[k * 64 + d];
    float a2[N], h[N];
    size_t o = (size_t)(bk * 128 + c) * N * 64 + d;
    #pragma unroll
    for (int n = 0; n < N; n++) { a2[n] = A2[(k * 64 + d) * N + n]; h[n] = Hin[o + n * 64]; }
    int l0 = c * 32;
    const float2* rp  = (const float2*)(r01 + (size_t)bk * LL * 2) + l0;
    const float4* Bp4 = (const float4*)(Bs + (size_t)bk * LL * N);
    const float4* Cp4 = (const float4*)(Cs + (size_t)bk * LL * N);
    const float*  xb  = xcT + (size_t)b * LL * 64;
    float* yo = yrT + (size_t)(k * BB + b) * LL * 64 + d;
    float2 rv[8];
    #pragma unroll
    for (int j = 0; j < 8; j++) rv[j] = rp[j];
    for (int tile = 0; tile < 4; tile++) {
        float2 rvn[8];
        if (tile < 3) {
            #pragma unroll
            for (int j = 0; j < 8; j++) rvn[j] = rp[(tile + 1) * 8 + j];
        }
        float dts[8];
        #pragma unroll
        for (int j = 0; j < 8; j++)
            dts[j] = softplusf(fmaf(rv[j].x, w0, fmaf(rv[j].y, w1, bd)));
        #pragma unroll
        for (int j = 0; j < 8; j++) {
            int l = l0 + tile * 8 + j;
            float dt = dts[j];
            int lm = dirmap(k, l);
            float du = dt * xb[(size_t)lm * 64 + d];
            float y = 0.f;
            #pragma unroll
            for (int n4 = 0; n4 < N / 4; n4++) {
                float4 bv = Bp4[(size_t)l * (N / 4) + n4];
                float4 cv = Cp4[(size_t)l * (N / 4) + n4];
                float bvs[4] = {bv.x, bv.y, bv.z, bv.w};
                float cvs[4] = {cv.x, cv.y, cv.z, cv.w};
                #pragma unroll
                for (int jj = 0; jj < 4; jj++) {
                    int n = n4 * 4 + jj;
                    float a = exp2fast(dt * a2[n]);
                    h[n] = fmaf(a, h[n], du * bvs[jj]);
                    y = fmaf(h[n], cvs[jj], y);
                }
            }
            yo[(size_t)lm * 64] = y;                // coalesced row write, already spatial
        }
        #pragma unroll
        for (int j = 0; j < 8; j++) rv[j] = rvn[j];
    }
}

// ---------------- combine 4 dirs + D + LN + SiLU(z) gate + out-proj ----------------
__global__ __launch_bounds__(256) void k_combine(const float* __restrict__ yrT, const float* __restrict__ xcT,
                          const float* __restrict__ zT, const float* __restrict__ Dp,
                          const float* __restrict__ ln_g, const float* __restrict__ ln_b,
                          const float* __restrict__ out_w, float* __restrict__ sbuf) {
    int blk = blockIdx.x;                            // b*128 + tile
    int l0 = (blk & 127) * 32; int b = blk >> 7;
    int tid = threadIdx.x;
    __shared__ float yt[32][65];                     // [q][d]
    __shared__ float yg[32][65];                     // [q][d]
    __shared__ float muS[32], rsS[32];
    const size_t DS = (size_t)BB * LL * 64;
    for (int i = tid; i < 2048; i += 256) {
        int d = i & 63, q = i >> 6;
        size_t st = ((size_t)b * LL + l0 + q) * 64 + d;
        float yv = yrT[st] + yrT[DS + st] + yrT[2 * DS + st] + yrT[3 * DS + st];
        float sd = Dp[d] + Dp[64 + d] + Dp[128 + d] + Dp[192 + d];
        yt[q][d] = fmaf(xcT[st], sd, yv);
    }
    __syncthreads();
    {
        int q = tid >> 3, sub = tid & 7;             // 8 lanes per q, aligned in-wave
        float s = 0.f, sq = 0.f;
        #pragma unroll
        for (int j = 0; j < 8; j++) {
            float vv = yt[q][sub * 8 + j]; s += vv; sq = fmaf(vv, vv, sq);
        }
        #pragma unroll
        for (int m = 1; m < 8; m <<= 1) {
            s += __shfl_xor(s, m, 64); sq += __shfl_xor(sq, m, 64);
        }
        if (sub == 0) {
            float mm = s * (1.f / 64.f);
            muS[q] = mm;
            rsS[q] = rsqrtf(fmaf(sq, 1.f / 64.f, -mm * mm) + 1e-5f);
        }
    }
    __syncthreads();
    for (int i = tid; i < 2048; i += 256) {
        int d = i & 63, q = i >> 6;
        float gn = fmaf((yt[q][d] - muS[q]) * rsS[q], ln_g[d], ln_b[d]);
        float z = zT[((size_t)b * LL + l0 + q) * 64 + d];
        yg[q][d] = gn * z / (1.f + expf(-z));
    }
    __syncthreads();
    for (int i = tid; i < 32 * 32; i += 256) {
        int e = i >> 5, q = i & 31;
        const float* wr = out_w + e * 64;
        float acc = 0.f;
        #pragma unroll 8
        for (int d = 0; d < 64; d++) acc += wr[d] * yg[q][d];
        sbuf[((size_t)b * 32 + e) * LL + l0 + q] = acc;
    }
}

// ---------------- g-tail: 1x1 conv over [s ; pool] + BN + ReLU (4 px/thread) ----------------
__global__ __launch_bounds__(256) void k_gtail(const float* __restrict__ sbuf, const float* __restrict__ pw,
                        const float* __restrict__ gfpool, int poolOff, int poolOff2,
                        const float* __restrict__ g, const float* __restrict__ bt,
                        const float* __restrict__ m, const float* __restrict__ v,
                        float* __restrict__ out) {
    int i = blockIdx.x * 256 + threadIdx.x;          // B*32*(L/4)
    int l4 = i & 1023; int co = (i >> 10) & 31; int b = i >> 15;
    int l = l4 << 2;
    const float* pwr = pw + co * 64;
    float pacc = 0.f;
    #pragma unroll 8
    for (int c = 0; c < 32; c++) {
        float pv = gfpool[b * 128 + poolOff + c];
        if (poolOff2 >= 0) pv += gfpool[b * 128 + poolOff2 + c];
        pacc = fmaf(pwr[32 + c], pv, pacc);
    }
    float a0 = pacc, a1 = pacc, a2 = pacc, a3 = pacc;
    const float* sb = sbuf + (size_t)b * 32 * LL + l;
    #pragma unroll 8
    for (int c = 0; c < 32; c++) {
        float4 sv = *(const float4*)(sb + (size_t)c * LL);
        float wk = pwr[c];
        a0 = fmaf(wk, sv.x, a0);
        a1 = fmaf(wk, sv.y, a1);
        a2 = fmaf(wk, sv.z, a2);
        a3 = fmaf(wk, sv.w, a3);
    }
    float sc = g[co] * rsqrtf(v[co] + 1e-5f);
    float bs = bt[co] - m[co] * sc;
    float4 o;
    o.x = fmaxf(fmaf(a0, sc, bs), 0.f);
    o.y = fmaxf(fmaf(a1, sc, bs), 0.f);
    o.z = fmaxf(fmaf(a2, sc, bs), 0.f);
    o.w = fmaxf(fmaf(a3, sc, bs), 0.f);
    *(float4*)(out + (size_t)(b * 32 + co) * LL + l) = o;
}

// ---------------- gf (global feature) + pgf (its proj_w contribution) ----------------
__global__ void k_gf(const float* __restrict__ gfpool, const float* __restrict__ gp_w,
                     const float* __restrict__ proj_w, float* __restrict__ gf, float* __restrict__ pgf) {
    __shared__ float gfl[4][128];
    int t = threadIdx.x;                             // 512
    int b = t >> 7, e = t & 127;
    float acc = 0.f;
    for (int c = 0; c < 128; c++) acc += gp_w[e * 128 + c] * gfpool[b * 128 + c];
    acc = fmaxf(acc, 0.f);
    gf[b * 128 + e] = acc; gfl[b][e] = acc;
    __syncthreads();
    float a2 = 0.f;
    for (int c = 0; c < 128; c++) a2 += proj_w[e * 256 + 128 + c] * gfl[b][c];
    pgf[b * 128 + e] = a2;
}

// ---------------- proj: 1x1 conv over [fused ; gf] + BN + ReLU + residual (4 px/thread) ----------------
__global__ __launch_bounds__(256) void k_proj(const float* __restrict__ x,
                       const float* __restrict__ o1, const float* __restrict__ o2,
                       const float* __restrict__ o3, const float* __restrict__ o4,
                       const float* __restrict__ proj_w, const float* __restrict__ pgf,
                       const float* __restrict__ g, const float* __restrict__ bt,
                       const float* __restrict__ m, const float* __restrict__ v,
                       float* __restrict__ ybuf) {
    int i = blockIdx.x * 256 + threadIdx.x;          // B*128*(L/4)
    int l4 = i & 1023; int co = (i >> 10) & 127; int b = i >> 17;
    int l = l4 << 2;
    const float* wr = proj_w + co * 256;
    float pg = pgf[b * 128 + co];
    float a0 = pg, a1 = pg, a2 = pg, a3 = pg;
    size_t ob = (size_t)b * 32 * LL + l;
    #pragma unroll 8
    for (int c = 0; c < 32; c++) {
        float4 vv = *(const float4*)(o1 + ob + (size_t)c * LL);
        float wk = wr[c];
        a0 = fmaf(wk, vv.x, a0); a1 = fmaf(wk, vv.y, a1);
        a2 = fmaf(wk, vv.z, a2); a3 = fmaf(wk, vv.w, a3);
    }
    #pragma unroll 8
    for (int c = 0; c < 32; c++) {
        float4 vv = *(const float4*)(o2 + ob + (size_t)c * LL);
        float wk = wr[32 + c];
        a0 = fmaf(wk, vv.x, a0); a1 = fmaf(wk, vv.y, a1);
        a2 = fmaf(wk, vv.z, a2); a3 = fmaf(wk, vv.w, a3);
    }
    #pragma unroll 8
    for (int c = 0; c < 32; c++) {
        float4 vv = *(const float4*)(o3 + ob + (size_t)c * LL);
        float wk = wr[64 + c];
        a0 = fmaf(wk, vv.x, a0); a1 = fmaf(wk, vv.y, a1);
        a2 = fmaf(wk, vv.z, a2); a3 = fmaf(wk, vv.w, a3);
    }
    #pragma unroll 8
    for (int c = 0; c < 32; c++) {
        float4 vv = *(const float4*)(o4 + ob + (size_t)c * LL);
        float wk = wr[96 + c];
        a0 = fmaf(wk, vv.x, a0); a1 = fmaf(wk, vv.y, a1);
        a2 = fmaf(wk, vv.z, a2); a3 = fmaf(wk, vv.w, a3);
    }
    float sc = g[co] * rsqrtf(v[co] + 1e-5f);
    float bs = bt[co] - m[co] * sc;
    float4 xv = *(const float4*)(x + (size_t)(b * 128 + co) * LL + l);
    float4 o;
    o.x = xv.x + fmaxf(fmaf(a0, sc, bs), 0.f);
    o.y = xv.y + fmaxf(fmaf(a1, sc, bs), 0.f);
    o.z = xv.z + fmaxf(fmaf(a2, sc, bs), 0.f);
    o.w = xv.w + fmaxf(fmaf(a3, sc, bs), 0.f);
    *(float4*)(ybuf + (size_t)(b * 128 + co) * LL + l) = o;
}

// ---------------- channel attention ----------------
__global__ void k_ca(const float* __restrict__ ypool, const float* __restrict__ w1,
                     const float* __restrict__ b1, const float* __restrict__ w2,
                     const float* __restrict__ b2, float* __restrict__ ca) {
    int b = blockIdx.x; int t = threadIdx.x;         // 128
    __shared__ float ym[128]; __shared__ float r1[8];
    ym[t] = ypool[b * 128 + t];
    __syncthreads();
    if (t < 8) {
        float a = b1[t];
        for (int c = 0; c < 128; c++) a += w1[t * 128 + c] * ym[c];
        r1[t] = fmaxf(a, 0.f);
    }
    __syncthreads();
    float a = b2[t];
    #pragma unroll
    for (int i2 = 0; i2 < 8; i2++) a += w2[t * 8 + i2] * r1[i2];
    ca[b * 128 + t] = sigmf(a);
}

// ---------------- spatial attention, phase 1: partial 7x7 conv over 16-ch groups ----------------
__global__ __launch_bounds__(256) void k_sa_part(const float* __restrict__ ybuf, const float* __restrict__ sw,
                     float* __restrict__ pa) {
    __shared__ float wlds[16 * 49];
    __shared__ float rows[4][7][70];
    __shared__ float part[4][64];
    int cg = blockIdx.x & 7; int h = (blockIdx.x >> 3) & 63; int b = blockIdx.x >> 9;
    int lane = threadIdx.x & 63, wv = threadIdx.x >> 6;
    for (int i = threadIdx.x; i < 16 * 49; i += 256) wlds[i] = sw[cg * 16 * 49 + i];
    if (lane < 3) {
        #pragma unroll
        for (int r = 0; r < 7; r++) { rows[wv][r][lane] = 0.f; rows[wv][r][67 + lane] = 0.f; }
    }
    __syncthreads();
    float acc = 0.f;
    for (int it = 0; it < 4; it++) {                // uniform loop: all waves hit barriers
        int lc = it * 4 + wv; int c = cg * 16 + lc;
        const float* yp = ybuf + ((size_t)b * 128 + c) * LL;
        #pragma unroll
        for (int r = 0; r < 7; r++) {
            int hh = h + r - 3;
            rows[wv][r][3 + lane] = ((unsigned)hh < 64u) ? yp[hh * 64 + lane] : 0.f;
        }
        __syncthreads();
        const float* wp = wlds + lc * 49;
        #pragma unroll
        for (int kh = 0; kh < 7; kh++) {
            #pragma unroll
            for (int kw = 0; kw < 7; kw++) {
                acc = fmaf(wp[kh * 7 + kw], rows[wv][kh][lane + kw], acc);
            }
        }
        __syncthreads();
    }
    part[wv][lane] = acc;
    __syncthreads();
    if (threadIdx.x < 64) {
        float a = part[0][threadIdx.x] + part[1][threadIdx.x]
                + part[2][threadIdx.x] + part[3][threadIdx.x];
        pa[(size_t)cg * (BB * LL) + (size_t)b * LL + h * 64 + threadIdx.x] = a;
    }
}

// ---------------- spatial attention, phase 2: sum 8 partials + sigmoid ----------------
__global__ void k_sared(const float* __restrict__ pa, float* __restrict__ sa) {
    int i = blockIdx.x * 256 + threadIdx.x;          // B*L
    float s = 0.f;
    #pragma unroll
    for (int g = 0; g < 8; g++) s += pa[(size_t)g * (BB * LL) + i];
    sa[i] = sigmf(s);
}

// ---------------- final: out = y * (1 + ca*sa) ----------------
__global__ void k_final(const float* __restrict__ ybuf, const float* __restrict__ ca,
                        const float* __restrict__ sa, float* __restrict__ out) {
    int i = blockIdx.x * 256 + threadIdx.x;          // B*128*L
    int l = i & (LL - 1); int co = (i >> 12) & 127; int b = i >> 19;
    float y = ybuf[i];
    out[i] = y * (1.f + ca[b * 128 + co] * sa[b * 4096 + l]);
}

// ================= host =================
extern "C" void kernel_launch(void* const* d_in, const int* in_sizes, int n_in,
                              void* d_out, int out_size, void* d_ws, size_t ws_size,
                              hipStream_t stream) {
    const float* x        = (const float*)d_in[0];
    const float* conv1_w  = (const float*)d_in[1];
    const float* c1g = (const float*)d_in[2], *c1b = (const float*)d_in[3];
    const float* c1m = (const float*)d_in[4], *c1v = (const float*)d_in[5];
    const float* s2_inw   = (const float*)d_in[6];
    const float* s2_cw    = (const float*)d_in[7];
    const float* s2_cb    = (const float*)d_in[8];
    const float* s2_xpw   = (const float*)d_in[9];
    const float* s2_dtw   = (const float*)d_in[10];
    const float* s2_dtb   = (const float*)d_in[11];
    const float* s2_Alog  = (const float*)d_in[12];
    const float* s2_D     = (const float*)d_in[13];
    const float* s2_lng   = (const float*)d_in[14];
    const float* s2_lnb   = (const float*)d_in[15];
    const float* s2_outw  = (const float*)d_in[16];
    const float* g2_pw    = (const float*)d_in[17];
    const float* g2g = (const float*)d_in[18], *g2b = (const float*)d_in[19];
    const float* g2m = (const float*)d_in[20], *g2v = (const float*)d_in[21];
    const float* conv3_w  = (const float*)d_in[22];
    const float* s4_inw   = (const float*)d_in[23];
    const float* s4_cw    = (const float*)d_in[24];
    const float* s4_cb    = (const float*)d_in[25];
    const float* s4_xpw   = (const float*)d_in[26];
    const float* s4_dtw   = (const float*)d_in[27];
    const float* s4_dtb   = (const float*)d_in[28];
    const float* s4_Alog  = (const float*)d_in[29];
    const float* s4_D     = (const float*)d_in[30];
    const float* s4_lng   = (const float*)d_in[31];
    const float* s4_lnb   = (const float*)d_in[32];
    const float* s4_outw  = (const float*)d_in[33];
    const float* g4_pw    = (const float*)d_in[34];
    const float* g4g = (const float*)d_in[35], *g4b = (const float*)d_in[36];
    const float* g4m = (const float*)d_in[37], *g4v = (const float*)d_in[38];
    const float* gp_w     = (const float*)d_in[39];
    const float* proj_w   = (const float*)d_in[40];
    const float* pjg = (const float*)d_in[41], *pjb = (const float*)d_in[42];
    const float* pjm = (const float*)d_in[43], *pjv = (const float*)d_in[44];
    const float* ca_w1 = (const float*)d_in[45], *ca_b1 = (const float*)d_in[46];
    const float* ca_w2 = (const float*)d_in[47], *ca_b2 = (const float*)d_in[48];
    const float* sa_w  = (const float*)d_in[49];
    float* out = (float*)d_out;
    float* w = (float*)d_ws;

    // ---- workspace layout (floats), total 15,346,176 floats = 61.4 MB ----
    // persistent
    const size_t o_out1 = 0;                        // 524288
    const size_t o_out2 = 524288;
    const size_t o_out3 = 1048576;
    const size_t o_out4 = 1572864;
    const size_t o_x42  = 2097152;                  // 524288
    const size_t o_gfp  = 2621440;                  // 512
    const size_t o_gf   = 2621952;
    const size_t o_pgf  = 2622464;
    const size_t o_ypool= 2622976;
    const size_t o_ca   = 2623488;
    const size_t o_A2   = 2624000;                  // 2048
    const size_t o_A4   = 2626048;                  // 6144
    const size_t o_S    = 2632192;                  // 4,194,304-float region
    // o_S region hosts (disjoint lifetimes):
    //   x13 (addgroups->conv3L), xiT (s1->s2), Pp (scanA->scanB),
    //   yrT (scanC->combine),    ybuf+sa+sap (tail)
    const size_t o_x13  = o_S;
    const size_t o_xiT  = o_S;
    const size_t o_Pp   = o_S;
    const size_t o_yrT  = o_S;
    const size_t o_ybuf = o_S;
    const size_t o_sa   = o_S + 2097152;            //  16,384
    const size_t o_sap  = o_S + 2113536;            // 131,072 (8 partial sa maps)
    const size_t o_zT   = o_S + 4194304;            // 1,048,576
    const size_t o_xcT  = o_zT + 1048576;           // 1,048,576
    const size_t o_r01  = o_xcT + 1048576;          //   131,072
    const size_t o_Bs   = o_r01 + 131072;           // 1,572,864 (N=24 sizing)
    const size_t o_sbuf = o_Bs;                     //   524,288 (overlays Bs after scanC)
    const size_t o_Cs   = o_Bs + 1572864;           // 1,572,864
    const size_t o_Hl   = o_Cs + 1572864;           // 3,145,728 (scanA->scanC; Hin in-place)

    dim3 b256(256);
    // prep
    k_prepA<<<24, b256, 0, stream>>>(s2_Alog, s4_Alog, w + o_A2, w + o_A4);
    k_addgroups<<<2048, b256, 0, stream>>>(x, w + o_x13, w + o_x42);
    k_pool<<<512, b256, 0, stream>>>(x, w + o_gfp);
    k_conv1L<<<256, b256, 0, stream>>>(x, conv1_w, c1g, c1b, c1m, c1v, w + o_out1);
    k_conv3L<<<256, b256, 0, stream>>>(w + o_x13, conv3_w, w + o_out3);

    // ---- SS2D #1 (N=8, conv 3x3, input x[:,32:64]) ----
    {
        const int N = 8;
        k_s1<<<256, b256, 0, stream>>>(x, CCH * LL, 32, s2_inw, w + o_xiT, w + o_zT);
        k_s2<3><<<4096, b256, 0, stream>>>(w + o_xiT, s2_cw, s2_cb, w + o_xcT);
        k_s3<N><<<4096, b256, 0, stream>>>(w + o_xcT, s2_xpw, w + o_r01, w + o_Bs, w + o_Cs);
        k_scanA<N><<<512, b256, 0, stream>>>(w + o_r01, w + o_Bs, w + o_xcT, w + o_A2,
                                             s2_dtw, s2_dtb, w + o_Pp, w + o_Hl);
        k_scanB<N><<<(16 * N * 64 + 255) / 256, b256, 0, stream>>>(w + o_Pp, w + o_Hl);
        k_scanC<N><<<512, b256, 0, stream>>>(w + o_r01, w + o_Bs, w + o_Cs, w + o_xcT,
                                             w + o_A2, s2_dtw, s2_dtb, w + o_Hl, w + o_yrT);
        k_combine<<<512, b256, 0, stream>>>(w + o_yrT, w + o_xcT, w + o_zT, s2_D,
                                            s2_lng, s2_lnb, s2_outw, w + o_sbuf);
        k_gtail<<<512, b256, 0, stream>>>(w + o_sbuf, g2_pw, w + o_gfp, 32, -1,
                                          g2g, g2b, g2m, g2v, w + o_out2);
    }
    // ---- SS2D #2 (N=24, conv 7x7, input x42) ----
    {
        const int N = 24;
        k_s1<<<256, b256, 0, stream>>>(w + o_x42, 32 * LL, 0, s4_inw, w + o_xiT, w + o_zT);
        k_s2<7><<<4096, b256, 0, stream>>>(w + o_xiT, s4_cw, s4_cb, w + o_xcT);
        k_s3<N><<<4096, b256, 0, stream>>>(w + o_xcT, s4_xpw, w + o_r01, w + o_Bs, w + o_Cs);
        k_scanA<N><<<512, b256, 0, stream>>>(w + o_r01, w + o_Bs, w + o_xcT, w + o_A4,
                                             s4_dtw, s4_dtb, w + o_Pp, w + o_Hl);
        k_scanB<N><<<(16 * N * 64 + 255) / 256, b256, 0, stream>>>(w + o_Pp, w + o_Hl);
        k_scanC<N><<<512, b256, 0, stream>>>(w + o_r01, w + o_Bs, w + o_Cs, w + o_xcT,
                                             w + o_A4, s4_dtw, s4_dtb, w + o_Hl, w + o_yrT);
        k_combine<<<512, b256, 0, stream>>>(w + o_yrT, w + o_xcT, w + o_zT, s4_D,
                                            s4_lng, s4_lnb, s4_outw, w + o_sbuf);
        k_gtail<<<512, b256, 0, stream>>>(w + o_sbuf, g4_pw, w + o_gfp, 96, 32,
                                          g4g, g4b, g4m, g4v, w + o_out4);
    }

    // tail (o_S region free again: ybuf/sa/sap overlay it)
    k_gf<<<1, dim3(512), 0, stream>>>(w + o_gfp, gp_w, proj_w, w + o_gf, w + o_pgf);
    k_proj<<<2048, b256, 0, stream>>>(x, w + o_out1, w + o_out2, w + o_out3, w + o_out4,
                                      proj_w, w + o_pgf, pjg, pjb, pjm, pjv, w + o_ybuf);
    k_pool<<<512, b256, 0, stream>>>(w + o_ybuf, w + o_ypool);
    k_ca<<<4, dim3(128), 0, stream>>>(w + o_ypool, ca_w1, ca_b1, ca_w2, ca_b2, w + o_ca);
    k_sa_part<<<2048, b256, 0, stream>>>(w + o_ybuf, sa_w, w + o_sap);
    k_sared<<<64, b256, 0, stream>>>(w + o_sap, w + o_sa);
    k_final<<<8192, b256, 0, stream>>>(w + o_ybuf, w + o_ca, w + o_sa, out);
}

// Round 11
// 624.368 us; speedup vs baseline: 1.1179x; 1.1179x over previous
//
#include <hip/hip_runtime.h>
#include <math.h>

// Problem constants
#define BB 4
#define CCH 128
#define LL 4096
#define LOG2E 1.44269504088896340736f

__device__ __forceinline__ float exp2fast(float x) {
    float r; asm("v_exp_f32 %0, %1" : "=v"(r) : "v"(x)); return r;
}
__device__ __forceinline__ float softplusf(float x) {
    return x > 20.f ? x : log1pf(expf(x));
}
__device__ __forceinline__ float sigmf(float x) {
    return 1.f / (1.f + expf(-x));
}

// direction map: seq position -> source index in row-major (h*64+w) layout.
// dirmap(k,.) is an involution for every k.
__device__ __forceinline__ int dirmap(int k, int l) {
    if (k == 0) return l;
    if (k == 1) return ((l & 63) << 6) | (l >> 6);
    if (k == 2) return LL - 1 - l;
    int j = LL - 1 - l; return ((j & 63) << 6) | (j >> 6);
}

// ---------------- prep: A2[k,d,n] = -exp(A_log[k*64+d,n]) * log2(e) ----------------
__global__ void k_prepA(const float* __restrict__ Alog2, const float* __restrict__ Alog4,
                        float* __restrict__ A2_2, float* __restrict__ A2_4) {
    int i = blockIdx.x * 256 + threadIdx.x;
    if (i < 4 * 64 * 8)  A2_2[i] = -expf(Alog2[i]) * LOG2E;
    if (i < 4 * 64 * 24) A2_4[i] = -expf(Alog4[i]) * LOG2E;
}

// ---------------- x13 = x1 + x3 ; x42 = x4 + x2 (each (B,32,L)) ----------------
__global__ void k_addgroups(const float* __restrict__ x, float* __restrict__ x13, float* __restrict__ x42) {
    int i = blockIdx.x * 256 + threadIdx.x;        // over B*32*L
    int l = i & (LL - 1); int c = (i >> 12) & 31; int b = i >> 17;
    const float* xb = x + (size_t)b * CCH * LL;
    x13[i] = xb[(64 + c) * LL + l] + xb[(0 + c) * LL + l];
    x42[i] = xb[(96 + c) * LL + l] + xb[(32 + c) * LL + l];
}

// ---------------- channel means over L ----------------
__global__ void k_pool(const float* __restrict__ src, float* __restrict__ dst) {
    int bc = blockIdx.x;
    const float* p = src + (size_t)bc * LL;
    float s = 0.f;
    for (int i = threadIdx.x; i < LL; i += 256) s += p[i];
    for (int m = 32; m >= 1; m >>= 1) s += __shfl_xor(s, m, 64);
    __shared__ float ws[4];
    if ((threadIdx.x & 63) == 0) ws[threadIdx.x >> 6] = s;
    __syncthreads();
    if (threadIdx.x == 0) dst[bc] = (ws[0] + ws[1] + ws[2] + ws[3]) * (1.f / LL);
}

// ---------------- conv1 (3x3 pad1 +BN+ReLU), LDS-staged ----------------
__global__ __launch_bounds__(256) void k_conv1L(const float* __restrict__ x,
                        const float* __restrict__ w1,
                        const float* __restrict__ g, const float* __restrict__ bt,
                        const float* __restrict__ m, const float* __restrict__ v,
                        float* __restrict__ out1) {
    __shared__ float t[32][3][66];
    int b = blockIdx.x >> 6, h = blockIdx.x & 63;
    int lane = threadIdx.x & 63, wv = threadIdx.x >> 6;
    const float* xb = x + (size_t)b * CCH * LL;
    for (int i = threadIdx.x; i < 192; i += 256) {      // 32ci*3r*2 halo cols
        int ci = i / 6, rem = i % 6;
        t[ci][rem >> 1][(rem & 1) ? 65 : 0] = 0.f;
    }
    for (int i = threadIdx.x; i < 6144; i += 256) {     // interior, coalesced
        int ci = i / 192, rem = i % 192;
        int r = rem >> 6, col = rem & 63;
        int hh = h + r - 1;
        t[ci][r][col + 1] = ((unsigned)hh < 64u) ? xb[ci * LL + hh * 64 + col] : 0.f;
    }
    __syncthreads();
    float a[8];
    #pragma unroll
    for (int j = 0; j < 8; j++) a[j] = 0.f;
    for (int ci = 0; ci < 32; ci++) {
        #pragma unroll
        for (int r = 0; r < 3; r++) {
            float v0 = t[ci][r][lane];
            float v1 = t[ci][r][lane + 1];
            float v2 = t[ci][r][lane + 2];
            #pragma unroll
            for (int j = 0; j < 8; j++) {
                const float* wp = w1 + ((wv * 8 + j) * 32 + ci) * 9 + r * 3;
                a[j] = fmaf(wp[0], v0, fmaf(wp[1], v1, fmaf(wp[2], v2, a[j])));
            }
        }
    }
    #pragma unroll
    for (int j = 0; j < 8; j++) {
        int co = wv * 8 + j;
        float sc = g[co] * rsqrtf(v[co] + 1e-5f);
        float bs = bt[co] - m[co] * sc;
        out1[(size_t)(b * 32 + co) * LL + h * 64 + lane] = fmaxf(fmaf(a[j], sc, bs), 0.f);
    }
}

// ---------------- conv3 (3x3 dil12 pad12 + ReLU), LDS-staged, input x13 ----------------
__global__ __launch_bounds__(256) void k_conv3L(const float* __restrict__ x13,
                        const float* __restrict__ w3, float* __restrict__ out3) {
    __shared__ float t[32][3][88];                      // halo 12 each side
    int b = blockIdx.x >> 6, h = blockIdx.x & 63;
    int lane = threadIdx.x & 63, wv = threadIdx.x >> 6;
    const float* xb = x13 + (size_t)b * 32 * LL;
    for (int i = threadIdx.x; i < 2304; i += 256) {     // 32*3*24 halo cols
        int ci = i / 72, rem = i % 72;
        int r = rem / 24, cz = rem % 24;
        t[ci][r][(cz < 12) ? cz : (cz + 64)] = 0.f;
    }
    for (int i = threadIdx.x; i < 6144; i += 256) {     // interior, coalesced
        int ci = i / 192, rem = i % 192;
        int r = rem >> 6, col = rem & 63;
        int hh = h + (r - 1) * 12;
        t[ci][r][col + 12] = ((unsigned)hh < 64u) ? xb[ci * LL + hh * 64 + col] : 0.f;
    }
    __syncthreads();
    float a[8];
    #pragma unroll
    for (int j = 0; j < 8; j++) a[j] = 0.f;
    for (int ci = 0; ci < 32; ci++) {
        #pragma unroll
        for (int r = 0; r < 3; r++) {
            float v0 = t[ci][r][lane];
            float v1 = t[ci][r][lane + 12];
            float v2 = t[ci][r][lane + 24];
            #pragma unroll
            for (int j = 0; j < 8; j++) {
                const float* wp = w3 + ((wv * 8 + j) * 32 + ci) * 9 + r * 3;
                a[j] = fmaf(wp[0], v0, fmaf(wp[1], v1, fmaf(wp[2], v2, a[j])));
            }
        }
    }
    #pragma unroll
    for (int j = 0; j < 8; j++) {
        int co = wv * 8 + j;
        out3[(size_t)(b * 32 + co) * LL + h * 64 + lane] = fmaxf(a[j], 0.f);
    }
}

// ---------------- S1: in-proj 128x32 -> xiT (B,L,64), zT (B,L,64) ----------------
__global__ __launch_bounds__(256) void k_s1(const float* __restrict__ src, int bstride, int coff,
                     const float* __restrict__ in_w,
                     float* __restrict__ xiT, float* __restrict__ zT) {
    int blk = blockIdx.x;                           // B * (L/64)
    int l0 = (blk & 63) * 64; int b = blk >> 6;
    int lq = threadIdx.x & 63; int esub = threadIdx.x >> 6;
    __shared__ float xin[32][64];
    __shared__ float xit[64][65];
    __shared__ float zt[64][65];
    for (int i = threadIdx.x; i < 32 * 64; i += 256) {
        int c = i >> 6, q = i & 63;
        xin[c][q] = src[(size_t)b * bstride + (size_t)(coff + c) * LL + l0 + q];
    }
    __syncthreads();
    for (int it = 0; it < 32; it++) {
        int e = esub * 32 + it;
        const float* wr = in_w + e * 32;
        float acc = 0.f;
        #pragma unroll 8
        for (int c = 0; c < 32; c++) acc += wr[c] * xin[c][lq];
        if (e < 64) xit[lq][e] = acc;
        else        zt[lq][e - 64] = acc;
    }
    __syncthreads();
    for (int i = threadIdx.x; i < 64 * 64; i += 256) {
        int q = i >> 6, d = i & 63;
        size_t st = ((size_t)b * LL + l0 + q) * 64 + d;
        xiT[st] = xit[q][d];
        zT[st]  = zt[q][d];
    }
}

// ---------------- S2: depthwise KxK + bias + SiLU -> xcT (B,L,64) ----------------
template<int K>
__global__ __launch_bounds__(256) void k_s2(const float* __restrict__ xiT, const float* __restrict__ cw,
                     const float* __restrict__ cb, float* __restrict__ xcT) {
    __shared__ float wl[64 * K * K];
    for (int j = threadIdx.x; j < 64 * K * K; j += 256) wl[j] = cw[j];
    __syncthreads();
    int i = blockIdx.x * 256 + threadIdx.x;         // B*L*64, d inner
    int d = i & 63; int l = (i >> 6) & (LL - 1); int b = i >> 18;
    int h = l >> 6, wx = l & 63;
    const int P = (K - 1) / 2;
    const float* xb = xiT + (size_t)b * LL * 64;
    const float* wp = wl + d * K * K;
    float acc = cb[d];
    #pragma unroll
    for (int kh = 0; kh < K; kh++) {
        int hh = h + kh - P; if ((unsigned)hh >= 64u) continue;
        #pragma unroll
        for (int kw = 0; kw < K; kw++) {
            int w2 = wx + kw - P; if ((unsigned)w2 >= 64u) continue;
            acc += wp[kh * K + kw] * xb[(size_t)(hh * 64 + w2) * 64 + d];
        }
    }
    xcT[i] = acc / (1.f + expf(-acc));              // SiLU
}

// ---------------- S3: x_dbl proj -> r01 (bk,l,2), Bs (bk,l,N), Cs (bk,l,N) ----------------
template<int N>
__global__ __launch_bounds__(256) void k_s3(const float* __restrict__ xcT, const float* __restrict__ xp_w,
                     float* __restrict__ r01, float* __restrict__ Bsb, float* __restrict__ Csb) {
    const int CD = 2 + 2 * N;
    int blk = blockIdx.x;                           // b*4*256 tiles of 16
    int lt = blk & 255; int k = (blk >> 8) & 3; int b = blk >> 10;
    int l0 = lt * 16; int bk = b * 4 + k;
    __shared__ float xt[64][17];
    __shared__ float xp[CD * 64];
    __shared__ float accs[CD][16];
    for (int i = threadIdx.x; i < 64 * 16; i += 256) {
        int dd = i & 63, lq = i >> 6;
        xt[dd][lq] = xcT[((size_t)b * LL + dirmap(k, l0 + lq)) * 64 + dd];
    }
    for (int i = threadIdx.x; i < CD * 64; i += 256) xp[i] = xp_w[(size_t)k * CD * 64 + i];
    __syncthreads();
    for (int o = threadIdx.x; o < CD * 16; o += 256) {
        int cc = o >> 4, lq = o & 15;
        const float* wr = &xp[cc * 64];
        float acc = 0.f;
        #pragma unroll 8
        for (int dd = 0; dd < 64; dd++) acc += wr[dd] * xt[dd][lq];
        accs[cc][lq] = acc;
    }
    __syncthreads();
    for (int i = threadIdx.x; i < 32; i += 256) {
        int lq = i >> 1, j = i & 1;
        r01[((size_t)bk * LL + l0 + lq) * 2 + j] = accs[j][lq];
    }
    for (int i = threadIdx.x; i < 16 * N; i += 256) {
        int lq = i / N, n = i - lq * N;
        Bsb[((size_t)bk * LL + l0 + lq) * N + n] = accs[2 + n][lq];
        Csb[((size_t)bk * LL + l0 + lq) * N + n] = accs[2 + N + n][lq];
    }
}

// ---------------- scan phase A ----------------
// block = (bk, chunk of 32 steps); 4 waves split N into N/4 chains each
// (chains are independent in the recurrence). Grid 2048 blocks = 8 waves/SIMD
// (round-10: 2/SIMD was the latency bottleneck). Per-chunk operands staged in
// LDS: B (32xN coalesced) and fused (dt, dt*u) float2 table (computed once
// cooperatively). Per-chain accumulation order unchanged -> identical results.
template<int N>
__global__ __launch_bounds__(256) void k_scanA(
    const float* __restrict__ r01, const float* __restrict__ Bs,
    const float* __restrict__ xcT, const float* __restrict__ A2,
    const float* __restrict__ dtw, const float* __restrict__ dtb,
    float* __restrict__ Pp, float* __restrict__ Hl) {
    const int N4 = N / 4;
    __shared__ float2 dd2[32][64];                  // (dt, dt*u)
    __shared__ float lb[32 * N];
    int bk = blockIdx.x >> 7; int c = blockIdx.x & 127;
    int k = bk & 3, b = bk >> 2;
    int tid = threadIdx.x;
    int d = tid & 63, wv = tid >> 6;
    int l0 = c * 32;
    const float* Bp = Bs + ((size_t)bk * LL + l0) * N;
    for (int i = tid; i < 32 * N; i += 256) lb[i] = Bp[i];
    {
        float w0 = dtw[(k * 64 + d) * 2], w1 = dtw[(k * 64 + d) * 2 + 1], bd = dtb[k * 64 + d];
        const float2* rp = (const float2*)(r01 + (size_t)bk * LL * 2);
        const float* xb = xcT + (size_t)b * LL * 64;
        #pragma unroll
        for (int j = 0; j < 8; j++) {
            int t = wv * 8 + j;
            float2 rv = rp[l0 + t];
            float u = xb[(size_t)dirmap(k, l0 + t) * 64 + d];
            float dt = softplusf(fmaf(rv.x, w0, fmaf(rv.y, w1, bd)));
            dd2[t][d] = make_float2(dt, dt * u);
        }
    }
    __syncthreads();
    float a2[N4], h[N4], P[N4];
    #pragma unroll
    for (int n = 0; n < N4; n++) {
        a2[n] = A2[(k * 64 + d) * N + wv * N4 + n];
        h[n] = 0.f; P[n] = 1.f;
    }
    for (int t = 0; t < 32; t++) {
        float2 dv = dd2[t][d];
        const float* bl = &lb[t * N + wv * N4];
        #pragma unroll
        for (int n = 0; n < N4; n++) {
            float a = exp2fast(dv.x * a2[n]);
            P[n] *= a;
            h[n] = fmaf(a, h[n], dv.y * bl[n]);
        }
    }
    size_t o = (size_t)(bk * 128 + c) * N * 64 + d;
    #pragma unroll
    for (int n = 0; n < N4; n++) {
        Pp[o + (size_t)(wv * N4 + n) * 64] = P[n];
        Hl[o + (size_t)(wv * N4 + n) * 64] = h[n];
    }
}

// ---------------- scan phase B: sequential carry compose; Hin in-place over Hl ----------------
// next-iteration loads prefetched (independent of acc chain).
template<int N>
__global__ void k_scanB(const float* __restrict__ Pp, float* __restrict__ Hl) {
    int g = blockIdx.x * 256 + threadIdx.x;         // 16 * N * 64
    if (g >= 16 * N * 64) return;
    int d = g & 63; int n = (g >> 6) % N; int bk = g / (N * 64);
    const size_t stride = (size_t)N * 64;
    size_t o = (size_t)bk * 128 * stride + n * 64 + d;
    float acc = 0.f;
    float Pv = Pp[o], Hv = Hl[o];
    for (int c = 0; c < 128; c++) {
        float Pn = 0.f, Hn = 0.f;
        if (c < 127) { Pn = Pp[o + stride]; Hn = Hl[o + stride]; }
        Hl[o] = acc;                                // exclusive prefix = h_in for chunk c
        acc = fmaf(Pv, acc, Hv);
        Pv = Pn; Hv = Hn;
        o += stride;
    }
}

// ---------------- scan phase C: replay from h_in, emit y in spatial order ----------------
// Same n-split structure as scanA; cross-wave y reduction via 8-step-tiled LDS
// buffer (uniform barriers). B and C staged in LDS.
template<int N>
__global__ __launch_bounds__(256) void k_scanC(
    const float* __restrict__ r01, const float* __restrict__ Bs,
    const float* __restrict__ Cs, const float* __restrict__ xcT,
    const float* __restrict__ A2, const float* __restrict__ dtw,
    const float* __restrict__ dtb, const float* __restrict__ Hin,
    float* __restrict__ yrT) {
    const int N4 = N / 4;
    __shared__ float2 dd2[32][64];                  // (dt, dt*u)
    __shared__ float lb[32 * N];
    __shared__ float lc[32 * N];
    __shared__ float yacc[4][8][64];
    int bk = blockIdx.x >> 7; int c = blockIdx.x & 127;
    int k = bk & 3, b = bk >> 2;
    int tid = threadIdx.x;
    int d = tid & 63, wv = tid >> 6;
    int l0 = c * 32;
    const float* Bp = Bs + ((size_t)bk * LL + l0) * N;
    const float* Cp = Cs + ((size_t)bk * LL + l0) * N;
    for (int i = tid; i < 32 * N; i += 256) { lb[i] = Bp[i]; lc[i] = Cp[i]; }
    {
        float w0 = dtw[(k * 64 + d) * 2], w1 = dtw[(k * 64 + d) * 2 + 1], bd = dtb[k * 64 + d];
        const float2* rp = (const float2*)(r01 + (size_t)bk * LL * 2);
        const float* xb = xcT + (size_t)b * LL * 64;
        #pragma unroll
        for (int j = 0; j < 8; j++) {
            int t = wv * 8 + j;
            float2 rv = rp[l0 + t];
            float u = xb[(size_t)dirmap(k, l0 + t) * 64 + d];
            float dt = softplusf(fmaf(rv.x, w0, fmaf(rv.y, w1, bd)));
            dd2[t][d] = make_float2(dt, dt * u);
        }
    }
    float a2[N4], h[N4];
    size_t o = (size_t)(bk * 128 + c) * N * 64 + d;
    #pragma unroll
    for (int n = 0; n < N4; n++) {
        a2[n] = A2[(k * 64 + d) * N + wv * N4 + n];
        h[n] = Hin[o + (size_t)(wv * N4 + n) * 64];
    }
    __syncthreads();
    float* yo = yrT + (size_t)(k * BB + b) * LL * 64;
    for (int st = 0; st < 4; st++) {
        #pragma unroll
        for (int j = 0; j < 8; j++) {
            int t = st * 8 + j;
            float2 dv = dd2[t][d];
            const float* bl = &lb[t * N + wv * N4];
            const float* cl = &lc[t * N + wv * N4];
            float y = 0.f;
            #pragma unroll
            for (int n = 0; n < N4; n++) {
                float a = exp2fast(dv.x * a2[n]);
                h[n] = fmaf(a, h[n], dv.y * bl[n]);
                y = fmaf(h[n], cl[n], y);
            }
            yacc[wv][j][d] = y;
        }
        __syncthreads();
        for (int i = tid; i < 512; i += 256) {
            int j = i >> 6, q = i & 63;
            float y = yacc[0][j][q] + yacc[1][j][q] + yacc[2][j][q] + yacc[3][j][q];
            yo[(size_t)dirmap(k, l0 + st * 8 + j) * 64 + q] = y;
        }
        __syncthreads();
    }
}

// ---------------- combine 4 dirs + D + LN + SiLU(z) gate + out-proj ----------------
__global__ __launch_bounds__(256) void k_combine(const float* __restrict__ yrT, const float* __restrict__ xcT,
                          const float* __restrict__ zT, const float* __restrict__ Dp,
                          const float* __restrict__ ln_g, const float* __restrict__ ln_b,
                          const float* __restrict__ out_w, float* __restrict__ sbuf) {
    int blk = blockIdx.x;                            // b*128 + tile
    int l0 = (blk & 127) * 32; int b = blk >> 7;
    int tid = threadIdx.x;
    __shared__ float yt[32][65];                     // [q][d]
    __shared__ float yg[32][65];                     // [q][d]
    __shared__ float muS[32], rsS[32];
    const size_t DS = (size_t)BB * LL * 64;
    for (int i = tid; i < 2048; i += 256) {
        int d = i & 63, q = i >> 6;
        size_t st = ((size_t)b * LL + l0 + q) * 64 + d;
        float yv = yrT[st] + yrT[DS + st] + yrT[2 * DS + st] + yrT[3 * DS + st];
        float sd = Dp[d] + Dp[64 + d] + Dp[128 + d] + Dp[192 + d];
        yt[q][d] = fmaf(xcT[st], sd, yv);
    }
    __syncthreads();
    {
        int q = tid >> 3, sub = tid & 7;             // 8 lanes per q, aligned in-wave
        float s = 0.f, sq = 0.f;
        #pragma unroll
        for (int j = 0; j < 8; j++) {
            float vv = yt[q][sub * 8 + j]; s += vv; sq = fmaf(vv, vv, sq);
        }
        #pragma unroll
        for (int m = 1; m < 8; m <<= 1) {
            s += __shfl_xor(s, m, 64); sq += __shfl_xor(sq, m, 64);
        }
        if (sub == 0) {
            float mm = s * (1.f / 64.f);
            muS[q] = mm;
            rsS[q] = rsqrtf(fmaf(sq, 1.f / 64.f, -mm * mm) + 1e-5f);
        }
    }
    __syncthreads();
    for (int i = tid; i < 2048; i += 256) {
        int d = i & 63, q = i >> 6;
        float gn = fmaf((yt[q][d] - muS[q]) * rsS[q], ln_g[d], ln_b[d]);
        float z = zT[((size_t)b * LL + l0 + q) * 64 + d];
        yg[q][d] = gn * z / (1.f + expf(-z));
    }
    __syncthreads();
    for (int i = tid; i < 32 * 32; i += 256) {
        int e = i >> 5, q = i & 31;
        const float* wr = out_w + e * 64;
        float acc = 0.f;
        #pragma unroll 8
        for (int d = 0; d < 64; d++) acc += wr[d] * yg[q][d];
        sbuf[((size_t)b * 32 + e) * LL + l0 + q] = acc;
    }
}

// ---------------- g-tail: 1x1 conv over [s ; pool] + BN + ReLU (4 px/thread) ----------------
__global__ __launch_bounds__(256) void k_gtail(const float* __restrict__ sbuf, const float* __restrict__ pw,
                        const float* __restrict__ gfpool, int poolOff, int poolOff2,
                        const float* __restrict__ g, const float* __restrict__ bt,
                        const float* __restrict__ m, const float* __restrict__ v,
                        float* __restrict__ out) {
    int i = blockIdx.x * 256 + threadIdx.x;          // B*32*(L/4)
    int l4 = i & 1023; int co = (i >> 10) & 31; int b = i >> 15;
    int l = l4 << 2;
    const float* pwr = pw + co * 64;
    float pacc = 0.f;
    #pragma unroll 8
    for (int c = 0; c < 32; c++) {
        float pv = gfpool[b * 128 + poolOff + c];
        if (poolOff2 >= 0) pv += gfpool[b * 128 + poolOff2 + c];
        pacc = fmaf(pwr[32 + c], pv, pacc);
    }
    float a0 = pacc, a1 = pacc, a2 = pacc, a3 = pacc;
    const float* sb = sbuf + (size_t)b * 32 * LL + l;
    #pragma unroll 8
    for (int c = 0; c < 32; c++) {
        float4 sv = *(const float4*)(sb + (size_t)c * LL);
        float wk = pwr[c];
        a0 = fmaf(wk, sv.x, a0);
        a1 = fmaf(wk, sv.y, a1);
        a2 = fmaf(wk, sv.z, a2);
        a3 = fmaf(wk, sv.w, a3);
    }
    float sc = g[co] * rsqrtf(v[co] + 1e-5f);
    float bs = bt[co] - m[co] * sc;
    float4 o;
    o.x = fmaxf(fmaf(a0, sc, bs), 0.f);
    o.y = fmaxf(fmaf(a1, sc, bs), 0.f);
    o.z = fmaxf(fmaf(a2, sc, bs), 0.f);
    o.w = fmaxf(fmaf(a3, sc, bs), 0.f);
    *(float4*)(out + (size_t)(b * 32 + co) * LL + l) = o;
}

// ---------------- gf (global feature) + pgf (its proj_w contribution) ----------------
__global__ void k_gf(const float* __restrict__ gfpool, const float* __restrict__ gp_w,
                     const float* __restrict__ proj_w, float* __restrict__ gf, float* __restrict__ pgf) {
    __shared__ float gfl[4][128];
    int t = threadIdx.x;                             // 512
    int b = t >> 7, e = t & 127;
    float acc = 0.f;
    for (int c = 0; c < 128; c++) acc += gp_w[e * 128 + c] * gfpool[b * 128 + c];
    acc = fmaxf(acc, 0.f);
    gf[b * 128 + e] = acc; gfl[b][e] = acc;
    __syncthreads();
    float a2 = 0.f;
    for (int c = 0; c < 128; c++) a2 += proj_w[e * 256 + 128 + c] * gfl[b][c];
    pgf[b * 128 + e] = a2;
}

// ---------------- proj: 1x1 conv over [fused ; gf] + BN + ReLU + residual (4 px/thread) ----------------
__global__ __launch_bounds__(256) void k_proj(const float* __restrict__ x,
                       const float* __restrict__ o1, const float* __restrict__ o2,
                       const float* __restrict__ o3, const float* __restrict__ o4,
                       const float* __restrict__ proj_w, const float* __restrict__ pgf,
                       const float* __restrict__ g, const float* __restrict__ bt,
                       const float* __restrict__ m, const float* __restrict__ v,
                       float* __restrict__ ybuf) {
    int i = blockIdx.x * 256 + threadIdx.x;          // B*128*(L/4)
    int l4 = i & 1023; int co = (i >> 10) & 127; int b = i >> 17;
    int l = l4 << 2;
    const float* wr = proj_w + co * 256;
    float pg = pgf[b * 128 + co];
    float a0 = pg, a1 = pg, a2 = pg, a3 = pg;
    size_t ob = (size_t)b * 32 * LL + l;
    #pragma unroll 8
    for (int c = 0; c < 32; c++) {
        float4 vv = *(const float4*)(o1 + ob + (size_t)c * LL);
        float wk = wr[c];
        a0 = fmaf(wk, vv.x, a0); a1 = fmaf(wk, vv.y, a1);
        a2 = fmaf(wk, vv.z, a2); a3 = fmaf(wk, vv.w, a3);
    }
    #pragma unroll 8
    for (int c = 0; c < 32; c++) {
        float4 vv = *(const float4*)(o2 + ob + (size_t)c * LL);
        float wk = wr[32 + c];
        a0 = fmaf(wk, vv.x, a0); a1 = fmaf(wk, vv.y, a1);
        a2 = fmaf(wk, vv.z, a2); a3 = fmaf(wk, vv.w, a3);
    }
    #pragma unroll 8
    for (int c = 0; c < 32; c++) {
        float4 vv = *(const float4*)(o3 + ob + (size_t)c * LL);
        float wk = wr[64 + c];
        a0 = fmaf(wk, vv.x, a0); a1 = fmaf(wk, vv.y, a1);
        a2 = fmaf(wk, vv.z, a2); a3 = fmaf(wk, vv.w, a3);
    }
    #pragma unroll 8
    for (int c = 0; c < 32; c++) {
        float4 vv = *(const float4*)(o4 + ob + (size_t)c * LL);
        float wk = wr[96 + c];
        a0 = fmaf(wk, vv.x, a0); a1 = fmaf(wk, vv.y, a1);
        a2 = fmaf(wk, vv.z, a2); a3 = fmaf(wk, vv.w, a3);
    }
    float sc = g[co] * rsqrtf(v[co] + 1e-5f);
    float bs = bt[co] - m[co] * sc;
    float4 xv = *(const float4*)(x + (size_t)(b * 128 + co) * LL + l);
    float4 o;
    o.x = xv.x + fmaxf(fmaf(a0, sc, bs), 0.f);
    o.y = xv.y + fmaxf(fmaf(a1, sc, bs), 0.f);
    o.z = xv.z + fmaxf(fmaf(a2, sc, bs), 0.f);
    o.w = xv.w + fmaxf(fmaf(a3, sc, bs), 0.f);
    *(float4*)(ybuf + (size_t)(b * 128 + co) * LL + l) = o;
}

// ---------------- channel attention ----------------
__global__ void k_ca(const float* __restrict__ ypool, const float* __restrict__ w1,
                     const float* __restrict__ b1, const float* __restrict__ w2,
                     const float* __restrict__ b2, float* __restrict__ ca) {
    int b = blockIdx.x; int t = threadIdx.x;         // 128
    __shared__ float ym[128]; __shared__ float r1[8];
    ym[t] = ypool[b * 128 + t];
    __syncthreads();
    if (t < 8) {
        float a = b1[t];
        for (int c = 0; c < 128; c++) a += w1[t * 128 + c] * ym[c];
        r1[t] = fmaxf(a, 0.f);
    }
    __syncthreads();
    float a = b2[t];
    #pragma unroll
    for (int i2 = 0; i2 < 8; i2++) a += w2[t * 8 + i2] * r1[i2];
    ca[b * 128 + t] = sigmf(a);
}

// ---------------- spatial attention, phase 1: partial 7x7 conv over 16-ch groups ----------------
__global__ __launch_bounds__(256) void k_sa_part(const float* __restrict__ ybuf, const float* __restrict__ sw,
                     float* __restrict__ pa) {
    __shared__ float wlds[16 * 49];
    __shared__ float rows[4][7][70];
    __shared__ float part[4][64];
    int cg = blockIdx.x & 7; int h = (blockIdx.x >> 3) & 63; int b = blockIdx.x >> 9;
    int lane = threadIdx.x & 63, wv = threadIdx.x >> 6;
    for (int i = threadIdx.x; i < 16 * 49; i += 256) wlds[i] = sw[cg * 16 * 49 + i];
    if (lane < 3) {
        #pragma unroll
        for (int r = 0; r < 7; r++) { rows[wv][r][lane] = 0.f; rows[wv][r][67 + lane] = 0.f; }
    }
    __syncthreads();
    float acc = 0.f;
    for (int it = 0; it < 4; it++) {                // uniform loop: all waves hit barriers
        int lc = it * 4 + wv; int c = cg * 16 + lc;
        const float* yp = ybuf + ((size_t)b * 128 + c) * LL;
        #pragma unroll
        for (int r = 0; r < 7; r++) {
            int hh = h + r - 3;
            rows[wv][r][3 + lane] = ((unsigned)hh < 64u) ? yp[hh * 64 + lane] : 0.f;
        }
        __syncthreads();
        const float* wp = wlds + lc * 49;
        #pragma unroll
        for (int kh = 0; kh < 7; kh++) {
            #pragma unroll
            for (int kw = 0; kw < 7; kw++) {
                acc = fmaf(wp[kh * 7 + kw], rows[wv][kh][lane + kw], acc);
            }
        }
        __syncthreads();
    }
    part[wv][lane] = acc;
    __syncthreads();
    if (threadIdx.x < 64) {
        float a = part[0][threadIdx.x] + part[1][threadIdx.x]
                + part[2][threadIdx.x] + part[3][threadIdx.x];
        pa[(size_t)cg * (BB * LL) + (size_t)b * LL + h * 64 + threadIdx.x] = a;
    }
}

// ---------------- spatial attention, phase 2: sum 8 partials + sigmoid ----------------
__global__ void k_sared(const float* __restrict__ pa, float* __restrict__ sa) {
    int i = blockIdx.x * 256 + threadIdx.x;          // B*L
    float s = 0.f;
    #pragma unroll
    for (int g = 0; g < 8; g++) s += pa[(size_t)g * (BB * LL) + i];
    sa[i] = sigmf(s);
}

// ---------------- final: out = y * (1 + ca*sa) ----------------
__global__ void k_final(const float* __restrict__ ybuf, const float* __restrict__ ca,
                        const float* __restrict__ sa, float* __restrict__ out) {
    int i = blockIdx.x * 256 + threadIdx.x;          // B*128*L
    int l = i & (LL - 1); int co = (i >> 12) & 127; int b = i >> 19;
    float y = ybuf[i];
    out[i] = y * (1.f + ca[b * 128 + co] * sa[b * 4096 + l]);
}

// ================= host =================
extern "C" void kernel_launch(void* const* d_in, const int* in_sizes, int n_in,
                              void* d_out, int out_size, void* d_ws, size_t ws_size,
                              hipStream_t stream) {
    const float* x        = (const float*)d_in[0];
    const float* conv1_w  = (const float*)d_in[1];
    const float* c1g = (const float*)d_in[2], *c1b = (const float*)d_in[3];
    const float* c1m = (const float*)d_in[4], *c1v = (const float*)d_in[5];
    const float* s2_inw   = (const float*)d_in[6];
    const float* s2_cw    = (const float*)d_in[7];
    const float* s2_cb    = (const float*)d_in[8];
    const float* s2_xpw   = (const float*)d_in[9];
    const float* s2_dtw   = (const float*)d_in[10];
    const float* s2_dtb   = (const float*)d_in[11];
    const float* s2_Alog  = (const float*)d_in[12];
    const float* s2_D     = (const float*)d_in[13];
    const float* s2_lng   = (const float*)d_in[14];
    const float* s2_lnb   = (const float*)d_in[15];
    const float* s2_outw  = (const float*)d_in[16];
    const float* g2_pw    = (const float*)d_in[17];
    const float* g2g = (const float*)d_in[18], *g2b = (const float*)d_in[19];
    const float* g2m = (const float*)d_in[20], *g2v = (const float*)d_in[21];
    const float* conv3_w  = (const float*)d_in[22];
    const float* s4_inw   = (const float*)d_in[23];
    const float* s4_cw    = (const float*)d_in[24];
    const float* s4_cb    = (const float*)d_in[25];
    const float* s4_xpw   = (const float*)d_in[26];
    const float* s4_dtw   = (const float*)d_in[27];
    const float* s4_dtb   = (const float*)d_in[28];
    const float* s4_Alog  = (const float*)d_in[29];
    const float* s4_D     = (const float*)d_in[30];
    const float* s4_lng   = (const float*)d_in[31];
    const float* s4_lnb   = (const float*)d_in[32];
    const float* s4_outw  = (const float*)d_in[33];
    const float* g4_pw    = (const float*)d_in[34];
    const float* g4g = (const float*)d_in[35], *g4b = (const float*)d_in[36];
    const float* g4m = (const float*)d_in[37], *g4v = (const float*)d_in[38];
    const float* gp_w     = (const float*)d_in[39];
    const float* proj_w   = (const float*)d_in[40];
    const float* pjg = (const float*)d_in[41], *pjb = (const float*)d_in[42];
    const float* pjm = (const float*)d_in[43], *pjv = (const float*)d_in[44];
    const float* ca_w1 = (const float*)d_in[45], *ca_b1 = (const float*)d_in[46];
    const float* ca_w2 = (const float*)d_in[47], *ca_b2 = (const float*)d_in[48];
    const float* sa_w  = (const float*)d_in[49];
    float* out = (float*)d_out;
    float* w = (float*)d_ws;

    // ---- workspace layout (floats), total 15,346,176 floats = 61.4 MB ----
    // persistent
    const size_t o_out1 = 0;                        // 524288
    const size_t o_out2 = 524288;
    const size_t o_out3 = 1048576;
    const size_t o_out4 = 1572864;
    const size_t o_x42  = 2097152;                  // 524288
    const size_t o_gfp  = 2621440;                  // 512
    const size_t o_gf   = 2621952;
    const size_t o_pgf  = 2622464;
    const size_t o_ypool= 2622976;
    const size_t o_ca   = 2623488;
    const size_t o_A2   = 2624000;                  // 2048
    const size_t o_A4   = 2626048;                  // 6144
    const size_t o_S    = 2632192;                  // 4,194,304-float region
    // o_S region hosts (disjoint lifetimes):
    //   x13 (addgroups->conv3L), xiT (s1->s2), Pp (scanA->scanB),
    //   yrT (scanC->combine),    ybuf+sa+sap (tail)
    const size_t o_x13  = o_S;
    const size_t o_xiT  = o_S;
    const size_t o_Pp   = o_S;
    const size_t o_yrT  = o_S;
    const size_t o_ybuf = o_S;
    const size_t o_sa   = o_S + 2097152;            //  16,384
    const size_t o_sap  = o_S + 2113536;            // 131,072 (8 partial sa maps)
    const size_t o_zT   = o_S + 4194304;            // 1,048,576
    const size_t o_xcT  = o_zT + 1048576;           // 1,048,576
    const size_t o_r01  = o_xcT + 1048576;          //   131,072
    const size_t o_Bs   = o_r01 + 131072;           // 1,572,864 (N=24 sizing)
    const size_t o_sbuf = o_Bs;                     //   524,288 (overlays Bs after scanC)
    const size_t o_Cs   = o_Bs + 1572864;           // 1,572,864
    const size_t o_Hl   = o_Cs + 1572864;           // 3,145,728 (scanA->scanC; Hin in-place)

    dim3 b256(256);
    // prep
    k_prepA<<<24, b256, 0, stream>>>(s2_Alog, s4_Alog, w + o_A2, w + o_A4);
    k_addgroups<<<2048, b256, 0, stream>>>(x, w + o_x13, w + o_x42);
    k_pool<<<512, b256, 0, stream>>>(x, w + o_gfp);
    k_conv1L<<<256, b256, 0, stream>>>(x, conv1_w, c1g, c1b, c1m, c1v, w + o_out1);
    k_conv3L<<<256, b256, 0, stream>>>(w + o_x13, conv3_w, w + o_out3);

    // ---- SS2D #1 (N=8, conv 3x3, input x[:,32:64]) ----
    {
        const int N = 8;
        k_s1<<<256, b256, 0, stream>>>(x, CCH * LL, 32, s2_inw, w + o_xiT, w + o_zT);
        k_s2<3><<<4096, b256, 0, stream>>>(w + o_xiT, s2_cw, s2_cb, w + o_xcT);
        k_s3<N><<<4096, b256, 0, stream>>>(w + o_xcT, s2_xpw, w + o_r01, w + o_Bs, w + o_Cs);
        k_scanA<N><<<2048, b256, 0, stream>>>(w + o_r01, w + o_Bs, w + o_xcT, w + o_A2,
                                              s2_dtw, s2_dtb, w + o_Pp, w + o_Hl);
        k_scanB<N><<<(16 * N * 64 + 255) / 256, b256, 0, stream>>>(w + o_Pp, w + o_Hl);
        k_scanC<N><<<2048, b256, 0, stream>>>(w + o_r01, w + o_Bs, w + o_Cs, w + o_xcT,
                                              w + o_A2, s2_dtw, s2_dtb, w + o_Hl, w + o_yrT);
        k_combine<<<512, b256, 0, stream>>>(w + o_yrT, w + o_xcT, w + o_zT, s2_D,
                                            s2_lng, s2_lnb, s2_outw, w + o_sbuf);
        k_gtail<<<512, b256, 0, stream>>>(w + o_sbuf, g2_pw, w + o_gfp, 32, -1,
                                          g2g, g2b, g2m, g2v, w + o_out2);
    }
    // ---- SS2D #2 (N=24, conv 7x7, input x42) ----
    {
        const int N = 24;
        k_s1<<<256, b256, 0, stream>>>(w + o_x42, 32 * LL, 0, s4_inw, w + o_xiT, w + o_zT);
        k_s2<7><<<4096, b256, 0, stream>>>(w + o_xiT, s4_cw, s4_cb, w + o_xcT);
        k_s3<N><<<4096, b256, 0, stream>>>(w + o_xcT, s4_xpw, w + o_r01, w + o_Bs, w + o_Cs);
        k_scanA<N><<<2048, b256, 0, stream>>>(w + o_r01, w + o_Bs, w + o_xcT, w + o_A4,
                                              s4_dtw, s4_dtb, w + o_Pp, w + o_Hl);
        k_scanB<N><<<(16 * N * 64 + 255) / 256, b256, 0, stream>>>(w + o_Pp, w + o_Hl);
        k_scanC<N><<<2048, b256, 0, stream>>>(w + o_r01, w + o_Bs, w + o_Cs, w + o_xcT,
                                              w + o_A4, s4_dtw, s4_dtb, w + o_Hl, w + o_yrT);
        k_combine<<<512, b256, 0, stream>>>(w + o_yrT, w + o_xcT, w + o_zT, s4_D,
                                            s4_lng, s4_lnb, s4_outw, w + o_sbuf);
        k_gtail<<<512, b256, 0, stream>>>(w + o_sbuf, g4_pw, w + o_gfp, 96, 32,
                                          g4g, g4b, g4m, g4v, w + o_out4);
    }

    // tail (o_S region free again: ybuf/sa/sap overlay it)
    k_gf<<<1, dim3(512), 0, stream>>>(w + o_gfp, gp_w, proj_w, w + o_gf, w + o_pgf);
    k_proj<<<2048, b256, 0, stream>>>(x, w + o_out1, w + o_out2, w + o_out3, w + o_out4,
                                      proj_w, w + o_pgf, pjg, pjb, pjm, pjv, w + o_ybuf);
    k_pool<<<512, b256, 0, stream>>>(w + o_ybuf, w + o_ypool);
    k_ca<<<4, dim3(128), 0, stream>>>(w + o_ypool, ca_w1, ca_b1, ca_w2, ca_b2, w + o_ca);
    k_sa_part<<<2048, b256, 0, stream>>>(w + o_ybuf, sa_w, w + o_sap);
    k_sared<<<64, b256, 0, stream>>>(w + o_sap, w + o_sa);
    k_final<<<8192, b256, 0, stream>>>(w + o_ybuf, w + o_ca, w + o_sa, out);
}

// Round 12
// 578.536 us; speedup vs baseline: 1.2064x; 1.0792x over previous
//
#include <hip/hip_runtime.h>
#include <math.h>

// Problem constants
#define BB 4
#define CCH 128
#define LL 4096
#define LOG2E 1.44269504088896340736f

__device__ __forceinline__ float exp2fast(float x) {
    float r; asm("v_exp_f32 %0, %1" : "=v"(r) : "v"(x)); return r;
}
__device__ __forceinline__ float softplusf(float x) {
    return x > 20.f ? x : log1pf(expf(x));
}
__device__ __forceinline__ float sigmf(float x) {
    return 1.f / (1.f + expf(-x));
}

// direction map: seq position -> source index in row-major (h*64+w) layout.
// dirmap(k,.) is an involution for every k.
__device__ __forceinline__ int dirmap(int k, int l) {
    if (k == 0) return l;
    if (k == 1) return ((l & 63) << 6) | (l >> 6);
    if (k == 2) return LL - 1 - l;
    int j = LL - 1 - l; return ((j & 63) << 6) | (j >> 6);
}

// ---------------- prep: A2[k,d,n] = -exp(A_log[k*64+d,n]) * log2(e) ----------------
__global__ void k_prepA(const float* __restrict__ Alog2, const float* __restrict__ Alog4,
                        float* __restrict__ A2_2, float* __restrict__ A2_4) {
    int i = blockIdx.x * 256 + threadIdx.x;
    if (i < 4 * 64 * 8)  A2_2[i] = -expf(Alog2[i]) * LOG2E;
    if (i < 4 * 64 * 24) A2_4[i] = -expf(Alog4[i]) * LOG2E;
}

// ---------------- x13 = x1 + x3 ; x42 = x4 + x2 (each (B,32,L)) ----------------
__global__ void k_addgroups(const float* __restrict__ x, float* __restrict__ x13, float* __restrict__ x42) {
    int i = blockIdx.x * 256 + threadIdx.x;        // over B*32*L
    int l = i & (LL - 1); int c = (i >> 12) & 31; int b = i >> 17;
    const float* xb = x + (size_t)b * CCH * LL;
    x13[i] = xb[(64 + c) * LL + l] + xb[(0 + c) * LL + l];
    x42[i] = xb[(96 + c) * LL + l] + xb[(32 + c) * LL + l];
}

// ---------------- channel means over L ----------------
__global__ void k_pool(const float* __restrict__ src, float* __restrict__ dst) {
    int bc = blockIdx.x;
    const float* p = src + (size_t)bc * LL;
    float s = 0.f;
    for (int i = threadIdx.x; i < LL; i += 256) s += p[i];
    for (int m = 32; m >= 1; m >>= 1) s += __shfl_xor(s, m, 64);
    __shared__ float ws[4];
    if ((threadIdx.x & 63) == 0) ws[threadIdx.x >> 6] = s;
    __syncthreads();
    if (threadIdx.x == 0) dst[bc] = (ws[0] + ws[1] + ws[2] + ws[3]) * (1.f / LL);
}

// ---------------- conv1 (3x3 pad1 +BN+ReLU), LDS-staged ----------------
__global__ __launch_bounds__(256) void k_conv1L(const float* __restrict__ x,
                        const float* __restrict__ w1,
                        const float* __restrict__ g, const float* __restrict__ bt,
                        const float* __restrict__ m, const float* __restrict__ v,
                        float* __restrict__ out1) {
    __shared__ float t[32][3][66];
    int b = blockIdx.x >> 6, h = blockIdx.x & 63;
    int lane = threadIdx.x & 63, wv = threadIdx.x >> 6;
    const float* xb = x + (size_t)b * CCH * LL;
    for (int i = threadIdx.x; i < 192; i += 256) {      // 32ci*3r*2 halo cols
        int ci = i / 6, rem = i % 6;
        t[ci][rem >> 1][(rem & 1) ? 65 : 0] = 0.f;
    }
    for (int i = threadIdx.x; i < 6144; i += 256) {     // interior, coalesced
        int ci = i / 192, rem = i % 192;
        int r = rem >> 6, col = rem & 63;
        int hh = h + r - 1;
        t[ci][r][col + 1] = ((unsigned)hh < 64u) ? xb[ci * LL + hh * 64 + col] : 0.f;
    }
    __syncthreads();
    float a[8];
    #pragma unroll
    for (int j = 0; j < 8; j++) a[j] = 0.f;
    for (int ci = 0; ci < 32; ci++) {
        #pragma unroll
        for (int r = 0; r < 3; r++) {
            float v0 = t[ci][r][lane];
            float v1 = t[ci][r][lane + 1];
            float v2 = t[ci][r][lane + 2];
            #pragma unroll
            for (int j = 0; j < 8; j++) {
                const float* wp = w1 + ((wv * 8 + j) * 32 + ci) * 9 + r * 3;
                a[j] = fmaf(wp[0], v0, fmaf(wp[1], v1, fmaf(wp[2], v2, a[j])));
            }
        }
    }
    #pragma unroll
    for (int j = 0; j < 8; j++) {
        int co = wv * 8 + j;
        float sc = g[co] * rsqrtf(v[co] + 1e-5f);
        float bs = bt[co] - m[co] * sc;
        out1[(size_t)(b * 32 + co) * LL + h * 64 + lane] = fmaxf(fmaf(a[j], sc, bs), 0.f);
    }
}

// ---------------- conv3 (3x3 dil12 pad12 + ReLU), LDS-staged, input x13 ----------------
__global__ __launch_bounds__(256) void k_conv3L(const float* __restrict__ x13,
                        const float* __restrict__ w3, float* __restrict__ out3) {
    __shared__ float t[32][3][88];                      // halo 12 each side
    int b = blockIdx.x >> 6, h = blockIdx.x & 63;
    int lane = threadIdx.x & 63, wv = threadIdx.x >> 6;
    const float* xb = x13 + (size_t)b * 32 * LL;
    for (int i = threadIdx.x; i < 2304; i += 256) {     // 32*3*24 halo cols
        int ci = i / 72, rem = i % 72;
        int r = rem / 24, cz = rem % 24;
        t[ci][r][(cz < 12) ? cz : (cz + 64)] = 0.f;
    }
    for (int i = threadIdx.x; i < 6144; i += 256) {     // interior, coalesced
        int ci = i / 192, rem = i % 192;
        int r = rem >> 6, col = rem & 63;
        int hh = h + (r - 1) * 12;
        t[ci][r][col + 12] = ((unsigned)hh < 64u) ? xb[ci * LL + hh * 64 + col] : 0.f;
    }
    __syncthreads();
    float a[8];
    #pragma unroll
    for (int j = 0; j < 8; j++) a[j] = 0.f;
    for (int ci = 0; ci < 32; ci++) {
        #pragma unroll
        for (int r = 0; r < 3; r++) {
            float v0 = t[ci][r][lane];
            float v1 = t[ci][r][lane + 12];
            float v2 = t[ci][r][lane + 24];
            #pragma unroll
            for (int j = 0; j < 8; j++) {
                const float* wp = w3 + ((wv * 8 + j) * 32 + ci) * 9 + r * 3;
                a[j] = fmaf(wp[0], v0, fmaf(wp[1], v1, fmaf(wp[2], v2, a[j])));
            }
        }
    }
    #pragma unroll
    for (int j = 0; j < 8; j++) {
        int co = wv * 8 + j;
        out3[(size_t)(b * 32 + co) * LL + h * 64 + lane] = fmaxf(a[j], 0.f);
    }
}

// ---------------- S1: in-proj 128x32 -> xiT (B,L,64), zT (B,L,64) ----------------
__global__ __launch_bounds__(256) void k_s1(const float* __restrict__ src, int bstride, int coff,
                     const float* __restrict__ in_w,
                     float* __restrict__ xiT, float* __restrict__ zT) {
    int blk = blockIdx.x;                           // B * (L/64)
    int l0 = (blk & 63) * 64; int b = blk >> 6;
    int lq = threadIdx.x & 63; int esub = threadIdx.x >> 6;
    __shared__ float xin[32][64];
    __shared__ float xit[64][65];
    __shared__ float zt[64][65];
    for (int i = threadIdx.x; i < 32 * 64; i += 256) {
        int c = i >> 6, q = i & 63;
        xin[c][q] = src[(size_t)b * bstride + (size_t)(coff + c) * LL + l0 + q];
    }
    __syncthreads();
    for (int it = 0; it < 32; it++) {
        int e = esub * 32 + it;
        const float* wr = in_w + e * 32;
        float acc = 0.f;
        #pragma unroll 8
        for (int c = 0; c < 32; c++) acc += wr[c] * xin[c][lq];
        if (e < 64) xit[lq][e] = acc;
        else        zt[lq][e - 64] = acc;
    }
    __syncthreads();
    for (int i = threadIdx.x; i < 64 * 64; i += 256) {
        int q = i >> 6, d = i & 63;
        size_t st = ((size_t)b * LL + l0 + q) * 64 + d;
        xiT[st] = xit[q][d];
        zT[st]  = zt[q][d];
    }
}

// ---------------- S2: depthwise KxK + bias + SiLU -> xcT (B,L,64), 4 w/thread ----------------
// lane = d (coalesced); register sliding window over w: K+3 loads feed 4 outputs
// per row (round-11: 49x re-read of xiT made this L2-bound). Zero-padded OOB
// values replace branch skips (exact-0 adds are bit-identical).
template<int K>
__global__ __launch_bounds__(256) void k_s2(const float* __restrict__ xiT, const float* __restrict__ cw,
                     const float* __restrict__ cb, float* __restrict__ xcT) {
    const int P = (K - 1) / 2;
    __shared__ float wl[64 * K * K];
    for (int j = threadIdx.x; j < 64 * K * K; j += 256) wl[j] = cw[j];
    __syncthreads();
    int g = blockIdx.x * 4 + (threadIdx.x >> 6);    // over B*(L/4)
    int d = threadIdx.x & 63;
    int l4 = g & 1023; int b = g >> 10;
    int l = l4 << 2;
    int h = l >> 6, w0 = l & 63;
    const float* xb = xiT + (size_t)b * LL * 64;
    const float* wp = wl + d * K * K;
    float bias = cb[d];
    float a0 = bias, a1 = bias, a2 = bias, a3 = bias;
    #pragma unroll
    for (int kh = 0; kh < K; kh++) {
        int hh = h + kh - P; if ((unsigned)hh >= 64u) continue;
        float val[K + 3];
        #pragma unroll
        for (int j = 0; j < K + 3; j++) {
            int w2 = w0 + j - P;
            val[j] = ((unsigned)w2 < 64u) ? xb[(size_t)(hh * 64 + w2) * 64 + d] : 0.f;
        }
        #pragma unroll
        for (int kw = 0; kw < K; kw++) {
            float wk = wp[kh * K + kw];
            a0 = fmaf(wk, val[kw], a0);
            a1 = fmaf(wk, val[kw + 1], a1);
            a2 = fmaf(wk, val[kw + 2], a2);
            a3 = fmaf(wk, val[kw + 3], a3);
        }
    }
    size_t ob = ((size_t)b * LL + l) * 64 + d;
    xcT[ob]            = a0 / (1.f + expf(-a0));
    xcT[ob + 64]       = a1 / (1.f + expf(-a1));
    xcT[ob + 128]      = a2 / (1.f + expf(-a2));
    xcT[ob + 192]      = a3 / (1.f + expf(-a3));
}

// ---------------- S3: x_dbl proj -> r01 (bk,l,2), Bs (bk,l,N), Cs (bk,l,N) ----------------
template<int N>
__global__ __launch_bounds__(256) void k_s3(const float* __restrict__ xcT, const float* __restrict__ xp_w,
                     float* __restrict__ r01, float* __restrict__ Bsb, float* __restrict__ Csb) {
    const int CD = 2 + 2 * N;
    int blk = blockIdx.x;                           // b*4*256 tiles of 16
    int lt = blk & 255; int k = (blk >> 8) & 3; int b = blk >> 10;
    int l0 = lt * 16; int bk = b * 4 + k;
    __shared__ float xt[64][17];
    __shared__ float xp[CD * 64];
    __shared__ float accs[CD][16];
    for (int i = threadIdx.x; i < 64 * 16; i += 256) {
        int dd = i & 63, lq = i >> 6;
        xt[dd][lq] = xcT[((size_t)b * LL + dirmap(k, l0 + lq)) * 64 + dd];
    }
    for (int i = threadIdx.x; i < CD * 64; i += 256) xp[i] = xp_w[(size_t)k * CD * 64 + i];
    __syncthreads();
    for (int o = threadIdx.x; o < CD * 16; o += 256) {
        int cc = o >> 4, lq = o & 15;
        const float* wr = &xp[cc * 64];
        float acc = 0.f;
        #pragma unroll 8
        for (int dd = 0; dd < 64; dd++) acc += wr[dd] * xt[dd][lq];
        accs[cc][lq] = acc;
    }
    __syncthreads();
    for (int i = threadIdx.x; i < 32; i += 256) {
        int lq = i >> 1, j = i & 1;
        r01[((size_t)bk * LL + l0 + lq) * 2 + j] = accs[j][lq];
    }
    for (int i = threadIdx.x; i < 16 * N; i += 256) {
        int lq = i / N, n = i - lq * N;
        Bsb[((size_t)bk * LL + l0 + lq) * N + n] = accs[2 + n][lq];
        Csb[((size_t)bk * LL + l0 + lq) * N + n] = accs[2 + N + n][lq];
    }
}

// ---------------- scan phase A ----------------
template<int N>
__global__ __launch_bounds__(256) void k_scanA(
    const float* __restrict__ r01, const float* __restrict__ Bs,
    const float* __restrict__ xcT, const float* __restrict__ A2,
    const float* __restrict__ dtw, const float* __restrict__ dtb,
    float* __restrict__ Pp, float* __restrict__ Hl) {
    const int N4 = N / 4;
    __shared__ float2 dd2[32][64];                  // (dt, dt*u)
    __shared__ float lb[32 * N];
    int bk = blockIdx.x >> 7; int c = blockIdx.x & 127;
    int k = bk & 3, b = bk >> 2;
    int tid = threadIdx.x;
    int d = tid & 63, wv = tid >> 6;
    int l0 = c * 32;
    const float* Bp = Bs + ((size_t)bk * LL + l0) * N;
    for (int i = tid; i < 32 * N; i += 256) lb[i] = Bp[i];
    {
        float w0 = dtw[(k * 64 + d) * 2], w1 = dtw[(k * 64 + d) * 2 + 1], bd = dtb[k * 64 + d];
        const float2* rp = (const float2*)(r01 + (size_t)bk * LL * 2);
        const float* xb = xcT + (size_t)b * LL * 64;
        #pragma unroll
        for (int j = 0; j < 8; j++) {
            int t = wv * 8 + j;
            float2 rv = rp[l0 + t];
            float u = xb[(size_t)dirmap(k, l0 + t) * 64 + d];
            float dt = softplusf(fmaf(rv.x, w0, fmaf(rv.y, w1, bd)));
            dd2[t][d] = make_float2(dt, dt * u);
        }
    }
    __syncthreads();
    float a2[N4], h[N4], P[N4];
    #pragma unroll
    for (int n = 0; n < N4; n++) {
        a2[n] = A2[(k * 64 + d) * N + wv * N4 + n];
        h[n] = 0.f; P[n] = 1.f;
    }
    for (int t = 0; t < 32; t++) {
        float2 dv = dd2[t][d];
        const float* bl = &lb[t * N + wv * N4];
        #pragma unroll
        for (int n = 0; n < N4; n++) {
            float a = exp2fast(dv.x * a2[n]);
            P[n] *= a;
            h[n] = fmaf(a, h[n], dv.y * bl[n]);
        }
    }
    size_t o = (size_t)(bk * 128 + c) * N * 64 + d;
    #pragma unroll
    for (int n = 0; n < N4; n++) {
        Pp[o + (size_t)(wv * N4 + n) * 64] = P[n];
        Hl[o + (size_t)(wv * N4 + n) * 64] = h[n];
    }
}

// ---------------- scan phase B: sequential carry compose; Hin in-place over Hl ----------------
template<int N>
__global__ void k_scanB(const float* __restrict__ Pp, float* __restrict__ Hl) {
    int g = blockIdx.x * 256 + threadIdx.x;         // 16 * N * 64
    if (g >= 16 * N * 64) return;
    int d = g & 63; int n = (g >> 6) % N; int bk = g / (N * 64);
    const size_t stride = (size_t)N * 64;
    size_t o = (size_t)bk * 128 * stride + n * 64 + d;
    float acc = 0.f;
    float Pv = Pp[o], Hv = Hl[o];
    for (int c = 0; c < 128; c++) {
        float Pn = 0.f, Hn = 0.f;
        if (c < 127) { Pn = Pp[o + stride]; Hn = Hl[o + stride]; }
        Hl[o] = acc;                                // exclusive prefix = h_in for chunk c
        acc = fmaf(Pv, acc, Hv);
        Pv = Pn; Hv = Hn;
        o += stride;
    }
}

// ---------------- scan phase C: replay from h_in, emit y in spatial order ----------------
template<int N>
__global__ __launch_bounds__(256) void k_scanC(
    const float* __restrict__ r01, const float* __restrict__ Bs,
    const float* __restrict__ Cs, const float* __restrict__ xcT,
    const float* __restrict__ A2, const float* __restrict__ dtw,
    const float* __restrict__ dtb, const float* __restrict__ Hin,
    float* __restrict__ yrT) {
    const int N4 = N / 4;
    __shared__ float2 dd2[32][64];                  // (dt, dt*u)
    __shared__ float lb[32 * N];
    __shared__ float lc[32 * N];
    __shared__ float yacc[4][8][64];
    int bk = blockIdx.x >> 7; int c = blockIdx.x & 127;
    int k = bk & 3, b = bk >> 2;
    int tid = threadIdx.x;
    int d = tid & 63, wv = tid >> 6;
    int l0 = c * 32;
    const float* Bp = Bs + ((size_t)bk * LL + l0) * N;
    const float* Cp = Cs + ((size_t)bk * LL + l0) * N;
    for (int i = tid; i < 32 * N; i += 256) { lb[i] = Bp[i]; lc[i] = Cp[i]; }
    {
        float w0 = dtw[(k * 64 + d) * 2], w1 = dtw[(k * 64 + d) * 2 + 1], bd = dtb[k * 64 + d];
        const float2* rp = (const float2*)(r01 + (size_t)bk * LL * 2);
        const float* xb = xcT + (size_t)b * LL * 64;
        #pragma unroll
        for (int j = 0; j < 8; j++) {
            int t = wv * 8 + j;
            float2 rv = rp[l0 + t];
            float u = xb[(size_t)dirmap(k, l0 + t) * 64 + d];
            float dt = softplusf(fmaf(rv.x, w0, fmaf(rv.y, w1, bd)));
            dd2[t][d] = make_float2(dt, dt * u);
        }
    }
    float a2[N4], h[N4];
    size_t o = (size_t)(bk * 128 + c) * N * 64 + d;
    #pragma unroll
    for (int n = 0; n < N4; n++) {
        a2[n] = A2[(k * 64 + d) * N + wv * N4 + n];
        h[n] = Hin[o + (size_t)(wv * N4 + n) * 64];
    }
    __syncthreads();
    float* yo = yrT + (size_t)(k * BB + b) * LL * 64;
    for (int st = 0; st < 4; st++) {
        #pragma unroll
        for (int j = 0; j < 8; j++) {
            int t = st * 8 + j;
            float2 dv = dd2[t][d];
            const float* bl = &lb[t * N + wv * N4];
            const float* cl = &lc[t * N + wv * N4];
            float y = 0.f;
            #pragma unroll
            for (int n = 0; n < N4; n++) {
                float a = exp2fast(dv.x * a2[n]);
                h[n] = fmaf(a, h[n], dv.y * bl[n]);
                y = fmaf(h[n], cl[n], y);
            }
            yacc[wv][j][d] = y;
        }
        __syncthreads();
        for (int i = tid; i < 512; i += 256) {
            int j = i >> 6, q = i & 63;
            float y = yacc[0][j][q] + yacc[1][j][q] + yacc[2][j][q] + yacc[3][j][q];
            yo[(size_t)dirmap(k, l0 + st * 8 + j) * 64 + q] = y;
        }
        __syncthreads();
    }
}

// ---------------- combine 4 dirs + D + LN + SiLU(z) gate + out-proj ----------------
__global__ __launch_bounds__(256) void k_combine(const float* __restrict__ yrT, const float* __restrict__ xcT,
                          const float* __restrict__ zT, const float* __restrict__ Dp,
                          const float* __restrict__ ln_g, const float* __restrict__ ln_b,
                          const float* __restrict__ out_w, float* __restrict__ sbuf) {
    int blk = blockIdx.x;                            // b*128 + tile
    int l0 = (blk & 127) * 32; int b = blk >> 7;
    int tid = threadIdx.x;
    __shared__ float yt[32][65];                     // [q][d]
    __shared__ float yg[32][65];                     // [q][d]
    __shared__ float muS[32], rsS[32];
    const size_t DS = (size_t)BB * LL * 64;
    for (int i = tid; i < 2048; i += 256) {
        int d = i & 63, q = i >> 6;
        size_t st = ((size_t)b * LL + l0 + q) * 64 + d;
        float yv = yrT[st] + yrT[DS + st] + yrT[2 * DS + st] + yrT[3 * DS + st];
        float sd = Dp[d] + Dp[64 + d] + Dp[128 + d] + Dp[192 + d];
        yt[q][d] = fmaf(xcT[st], sd, yv);
    }
    __syncthreads();
    {
        int q = tid >> 3, sub = tid & 7;             // 8 lanes per q, aligned in-wave
        float s = 0.f, sq = 0.f;
        #pragma unroll
        for (int j = 0; j < 8; j++) {
            float vv = yt[q][sub * 8 + j]; s += vv; sq = fmaf(vv, vv, sq);
        }
        #pragma unroll
        for (int m = 1; m < 8; m <<= 1) {
            s += __shfl_xor(s, m, 64); sq += __shfl_xor(sq, m, 64);
        }
        if (sub == 0) {
            float mm = s * (1.f / 64.f);
            muS[q] = mm;
            rsS[q] = rsqrtf(fmaf(sq, 1.f / 64.f, -mm * mm) + 1e-5f);
        }
    }
    __syncthreads();
    for (int i = tid; i < 2048; i += 256) {
        int d = i & 63, q = i >> 6;
        float gn = fmaf((yt[q][d] - muS[q]) * rsS[q], ln_g[d], ln_b[d]);
        float z = zT[((size_t)b * LL + l0 + q) * 64 + d];
        yg[q][d] = gn * z / (1.f + expf(-z));
    }
    __syncthreads();
    for (int i = tid; i < 32 * 32; i += 256) {
        int e = i >> 5, q = i & 31;
        const float* wr = out_w + e * 64;
        float acc = 0.f;
        #pragma unroll 8
        for (int d = 0; d < 64; d++) acc += wr[d] * yg[q][d];
        sbuf[((size_t)b * 32 + e) * LL + l0 + q] = acc;
    }
}

// ---------------- g-tail: 1x1 conv over [s ; pool] + BN + ReLU (4 px/thread) ----------------
__global__ __launch_bounds__(256) void k_gtail(const float* __restrict__ sbuf, const float* __restrict__ pw,
                        const float* __restrict__ gfpool, int poolOff, int poolOff2,
                        const float* __restrict__ g, const float* __restrict__ bt,
                        const float* __restrict__ m, const float* __restrict__ v,
                        float* __restrict__ out) {
    int i = blockIdx.x * 256 + threadIdx.x;          // B*32*(L/4)
    int l4 = i & 1023; int co = (i >> 10) & 31; int b = i >> 15;
    int l = l4 << 2;
    const float* pwr = pw + co * 64;
    float pacc = 0.f;
    #pragma unroll 8
    for (int c = 0; c < 32; c++) {
        float pv = gfpool[b * 128 + poolOff + c];
        if (poolOff2 >= 0) pv += gfpool[b * 128 + poolOff2 + c];
        pacc = fmaf(pwr[32 + c], pv, pacc);
    }
    float a0 = pacc, a1 = pacc, a2 = pacc, a3 = pacc;
    const float* sb = sbuf + (size_t)b * 32 * LL + l;
    #pragma unroll 8
    for (int c = 0; c < 32; c++) {
        float4 sv = *(const float4*)(sb + (size_t)c * LL);
        float wk = pwr[c];
        a0 = fmaf(wk, sv.x, a0);
        a1 = fmaf(wk, sv.y, a1);
        a2 = fmaf(wk, sv.z, a2);
        a3 = fmaf(wk, sv.w, a3);
    }
    float sc = g[co] * rsqrtf(v[co] + 1e-5f);
    float bs = bt[co] - m[co] * sc;
    float4 o;
    o.x = fmaxf(fmaf(a0, sc, bs), 0.f);
    o.y = fmaxf(fmaf(a1, sc, bs), 0.f);
    o.z = fmaxf(fmaf(a2, sc, bs), 0.f);
    o.w = fmaxf(fmaf(a3, sc, bs), 0.f);
    *(float4*)(out + (size_t)(b * 32 + co) * LL + l) = o;
}

// ---------------- gf (global feature) + pgf (its proj_w contribution) ----------------
__global__ void k_gf(const float* __restrict__ gfpool, const float* __restrict__ gp_w,
                     const float* __restrict__ proj_w, float* __restrict__ gf, float* __restrict__ pgf) {
    __shared__ float gfl[4][128];
    int t = threadIdx.x;                             // 512
    int b = t >> 7, e = t & 127;
    float acc = 0.f;
    for (int c = 0; c < 128; c++) acc += gp_w[e * 128 + c] * gfpool[b * 128 + c];
    acc = fmaxf(acc, 0.f);
    gf[b * 128 + e] = acc; gfl[b][e] = acc;
    __syncthreads();
    float a2 = 0.f;
    for (int c = 0; c < 128; c++) a2 += proj_w[e * 256 + 128 + c] * gfl[b][c];
    pgf[b * 128 + e] = a2;
}

// ---------------- proj: 1x1 conv + BN + ReLU + residual; 4 co x 4 l per thread ----------------
// Each float4 operand load feeds 16 FMAs (round-11: 128x re-read made this
// L2-bound at 48 us). Same c-order accumulation per output -> bit-identical.
__global__ __launch_bounds__(256) void k_proj(const float* __restrict__ x,
                       const float* __restrict__ o1, const float* __restrict__ o2,
                       const float* __restrict__ o3, const float* __restrict__ o4,
                       const float* __restrict__ proj_w, const float* __restrict__ pgf,
                       const float* __restrict__ g, const float* __restrict__ bt,
                       const float* __restrict__ m, const float* __restrict__ v,
                       float* __restrict__ ybuf) {
    int i = blockIdx.x * 256 + threadIdx.x;          // B * 32co4 * (L/4)
    int l4 = i & 1023; int cg = (i >> 10) & 31; int b = i >> 15;
    int l = l4 << 2; int co0 = cg << 2;
    float acc[4][4];
    #pragma unroll
    for (int j = 0; j < 4; j++) {
        float pg = pgf[b * 128 + co0 + j];
        #pragma unroll
        for (int q = 0; q < 4; q++) acc[j][q] = pg;
    }
    size_t ob = (size_t)b * 32 * LL + l;
    const float* wr = proj_w + co0 * 256;
    #pragma unroll 4
    for (int c = 0; c < 32; c++) {
        float4 vv = *(const float4*)(o1 + ob + (size_t)c * LL);
        #pragma unroll
        for (int j = 0; j < 4; j++) {
            float wk = wr[j * 256 + c];
            acc[j][0] = fmaf(wk, vv.x, acc[j][0]); acc[j][1] = fmaf(wk, vv.y, acc[j][1]);
            acc[j][2] = fmaf(wk, vv.z, acc[j][2]); acc[j][3] = fmaf(wk, vv.w, acc[j][3]);
        }
    }
    #pragma unroll 4
    for (int c = 0; c < 32; c++) {
        float4 vv = *(const float4*)(o2 + ob + (size_t)c * LL);
        #pragma unroll
        for (int j = 0; j < 4; j++) {
            float wk = wr[j * 256 + 32 + c];
            acc[j][0] = fmaf(wk, vv.x, acc[j][0]); acc[j][1] = fmaf(wk, vv.y, acc[j][1]);
            acc[j][2] = fmaf(wk, vv.z, acc[j][2]); acc[j][3] = fmaf(wk, vv.w, acc[j][3]);
        }
    }
    #pragma unroll 4
    for (int c = 0; c < 32; c++) {
        float4 vv = *(const float4*)(o3 + ob + (size_t)c * LL);
        #pragma unroll
        for (int j = 0; j < 4; j++) {
            float wk = wr[j * 256 + 64 + c];
            acc[j][0] = fmaf(wk, vv.x, acc[j][0]); acc[j][1] = fmaf(wk, vv.y, acc[j][1]);
            acc[j][2] = fmaf(wk, vv.z, acc[j][2]); acc[j][3] = fmaf(wk, vv.w, acc[j][3]);
        }
    }
    #pragma unroll 4
    for (int c = 0; c < 32; c++) {
        float4 vv = *(const float4*)(o4 + ob + (size_t)c * LL);
        #pragma unroll
        for (int j = 0; j < 4; j++) {
            float wk = wr[j * 256 + 96 + c];
            acc[j][0] = fmaf(wk, vv.x, acc[j][0]); acc[j][1] = fmaf(wk, vv.y, acc[j][1]);
            acc[j][2] = fmaf(wk, vv.z, acc[j][2]); acc[j][3] = fmaf(wk, vv.w, acc[j][3]);
        }
    }
    #pragma unroll
    for (int j = 0; j < 4; j++) {
        int co = co0 + j;
        float sc = g[co] * rsqrtf(v[co] + 1e-5f);
        float bs = bt[co] - m[co] * sc;
        float4 xv = *(const float4*)(x + (size_t)(b * 128 + co) * LL + l);
        float4 o;
        o.x = xv.x + fmaxf(fmaf(acc[j][0], sc, bs), 0.f);
        o.y = xv.y + fmaxf(fmaf(acc[j][1], sc, bs), 0.f);
        o.z = xv.z + fmaxf(fmaf(acc[j][2], sc, bs), 0.f);
        o.w = xv.w + fmaxf(fmaf(acc[j][3], sc, bs), 0.f);
        *(float4*)(ybuf + (size_t)(b * 128 + co) * LL + l) = o;
    }
}

// ---------------- channel attention ----------------
__global__ void k_ca(const float* __restrict__ ypool, const float* __restrict__ w1,
                     const float* __restrict__ b1, const float* __restrict__ w2,
                     const float* __restrict__ b2, float* __restrict__ ca) {
    int b = blockIdx.x; int t = threadIdx.x;         // 128
    __shared__ float ym[128]; __shared__ float r1[8];
    ym[t] = ypool[b * 128 + t];
    __syncthreads();
    if (t < 8) {
        float a = b1[t];
        for (int c = 0; c < 128; c++) a += w1[t * 128 + c] * ym[c];
        r1[t] = fmaxf(a, 0.f);
    }
    __syncthreads();
    float a = b2[t];
    #pragma unroll
    for (int i2 = 0; i2 < 8; i2++) a += w2[t * 8 + i2] * r1[i2];
    ca[b * 128 + t] = sigmf(a);
}

// ---------------- spatial attention, phase 1: partial 7x7 conv over 16-ch groups ----------------
__global__ __launch_bounds__(256) void k_sa_part(const float* __restrict__ ybuf, const float* __restrict__ sw,
                     float* __restrict__ pa) {
    __shared__ float wlds[16 * 49];
    __shared__ float rows[4][7][70];
    __shared__ float part[4][64];
    int cg = blockIdx.x & 7; int h = (blockIdx.x >> 3) & 63; int b = blockIdx.x >> 9;
    int lane = threadIdx.x & 63, wv = threadIdx.x >> 6;
    for (int i = threadIdx.x; i < 16 * 49; i += 256) wlds[i] = sw[cg * 16 * 49 + i];
    if (lane < 3) {
        #pragma unroll
        for (int r = 0; r < 7; r++) { rows[wv][r][lane] = 0.f; rows[wv][r][67 + lane] = 0.f; }
    }
    __syncthreads();
    float acc = 0.f;
    for (int it = 0; it < 4; it++) {                // uniform loop: all waves hit barriers
        int lc = it * 4 + wv; int c = cg * 16 + lc;
        const float* yp = ybuf + ((size_t)b * 128 + c) * LL;
        #pragma unroll
        for (int r = 0; r < 7; r++) {
            int hh = h + r - 3;
            rows[wv][r][3 + lane] = ((unsigned)hh < 64u) ? yp[hh * 64 + lane] : 0.f;
        }
        __syncthreads();
        const float* wp = wlds + lc * 49;
        #pragma unroll
        for (int kh = 0; kh < 7; kh++) {
            #pragma unroll
            for (int kw = 0; kw < 7; kw++) {
                acc = fmaf(wp[kh * 7 + kw], rows[wv][kh][lane + kw], acc);
            }
        }
        __syncthreads();
    }
    part[wv][lane] = acc;
    __syncthreads();
    if (threadIdx.x < 64) {
        float a = part[0][threadIdx.x] + part[1][threadIdx.x]
                + part[2][threadIdx.x] + part[3][threadIdx.x];
        pa[(size_t)cg * (BB * LL) + (size_t)b * LL + h * 64 + threadIdx.x] = a;
    }
}

// ---------------- spatial attention, phase 2: sum 8 partials + sigmoid ----------------
__global__ void k_sared(const float* __restrict__ pa, float* __restrict__ sa) {
    int i = blockIdx.x * 256 + threadIdx.x;          // B*L
    float s = 0.f;
    #pragma unroll
    for (int g = 0; g < 8; g++) s += pa[(size_t)g * (BB * LL) + i];
    sa[i] = sigmf(s);
}

// ---------------- final: out = y * (1 + ca*sa) ----------------
__global__ void k_final(const float* __restrict__ ybuf, const float* __restrict__ ca,
                        const float* __restrict__ sa, float* __restrict__ out) {
    int i = blockIdx.x * 256 + threadIdx.x;          // B*128*L
    int l = i & (LL - 1); int co = (i >> 12) & 127; int b = i >> 19;
    float y = ybuf[i];
    out[i] = y * (1.f + ca[b * 128 + co] * sa[b * 4096 + l]);
}

// ================= host =================
extern "C" void kernel_launch(void* const* d_in, const int* in_sizes, int n_in,
                              void* d_out, int out_size, void* d_ws, size_t ws_size,
                              hipStream_t stream) {
    const float* x        = (const float*)d_in[0];
    const float* conv1_w  = (const float*)d_in[1];
    const float* c1g = (const float*)d_in[2], *c1b = (const float*)d_in[3];
    const float* c1m = (const float*)d_in[4], *c1v = (const float*)d_in[5];
    const float* s2_inw   = (const float*)d_in[6];
    const float* s2_cw    = (const float*)d_in[7];
    const float* s2_cb    = (const float*)d_in[8];
    const float* s2_xpw   = (const float*)d_in[9];
    const float* s2_dtw   = (const float*)d_in[10];
    const float* s2_dtb   = (const float*)d_in[11];
    const float* s2_Alog  = (const float*)d_in[12];
    const float* s2_D     = (const float*)d_in[13];
    const float* s2_lng   = (const float*)d_in[14];
    const float* s2_lnb   = (const float*)d_in[15];
    const float* s2_outw  = (const float*)d_in[16];
    const float* g2_pw    = (const float*)d_in[17];
    const float* g2g = (const float*)d_in[18], *g2b = (const float*)d_in[19];
    const float* g2m = (const float*)d_in[20], *g2v = (const float*)d_in[21];
    const float* conv3_w  = (const float*)d_in[22];
    const float* s4_inw   = (const float*)d_in[23];
    const float* s4_cw    = (const float*)d_in[24];
    const float* s4_cb    = (const float*)d_in[25];
    const float* s4_xpw   = (const float*)d_in[26];
    const float* s4_dtw   = (const float*)d_in[27];
    const float* s4_dtb   = (const float*)d_in[28];
    const float* s4_Alog  = (const float*)d_in[29];
    const float* s4_D     = (const float*)d_in[30];
    const float* s4_lng   = (const float*)d_in[31];
    const float* s4_lnb   = (const float*)d_in[32];
    const float* s4_outw  = (const float*)d_in[33];
    const float* g4_pw    = (const float*)d_in[34];
    const float* g4g = (const float*)d_in[35], *g4b = (const float*)d_in[36];
    const float* g4m = (const float*)d_in[37], *g4v = (const float*)d_in[38];
    const float* gp_w     = (const float*)d_in[39];
    const float* proj_w   = (const float*)d_in[40];
    const float* pjg = (const float*)d_in[41], *pjb = (const float*)d_in[42];
    const float* pjm = (const float*)d_in[43], *pjv = (const float*)d_in[44];
    const float* ca_w1 = (const float*)d_in[45], *ca_b1 = (const float*)d_in[46];
    const float* ca_w2 = (const float*)d_in[47], *ca_b2 = (const float*)d_in[48];
    const float* sa_w  = (const float*)d_in[49];
    float* out = (float*)d_out;
    float* w = (float*)d_ws;

    // ---- workspace layout (floats), total 15,346,176 floats = 61.4 MB ----
    // persistent
    const size_t o_out1 = 0;                        // 524288
    const size_t o_out2 = 524288;
    const size_t o_out3 = 1048576;
    const size_t o_out4 = 1572864;
    const size_t o_x42  = 2097152;                  // 524288
    const size_t o_gfp  = 2621440;                  // 512
    const size_t o_gf   = 2621952;
    const size_t o_pgf  = 2622464;
    const size_t o_ypool= 2622976;
    const size_t o_ca   = 2623488;
    const size_t o_A2   = 2624000;                  // 2048
    const size_t o_A4   = 2626048;                  // 6144
    const size_t o_S    = 2632192;                  // 4,194,304-float region
    // o_S region hosts (disjoint lifetimes):
    //   x13 (addgroups->conv3L), xiT (s1->s2), Pp (scanA->scanB),
    //   yrT (scanC->combine),    ybuf+sa+sap (tail)
    const size_t o_x13  = o_S;
    const size_t o_xiT  = o_S;
    const size_t o_Pp   = o_S;
    const size_t o_yrT  = o_S;
    const size_t o_ybuf = o_S;
    const size_t o_sa   = o_S + 2097152;            //  16,384
    const size_t o_sap  = o_S + 2113536;            // 131,072 (8 partial sa maps)
    const size_t o_zT   = o_S + 4194304;            // 1,048,576
    const size_t o_xcT  = o_zT + 1048576;           // 1,048,576
    const size_t o_r01  = o_xcT + 1048576;          //   131,072
    const size_t o_Bs   = o_r01 + 131072;           // 1,572,864 (N=24 sizing)
    const size_t o_sbuf = o_Bs;                     //   524,288 (overlays Bs after scanC)
    const size_t o_Cs   = o_Bs + 1572864;           // 1,572,864
    const size_t o_Hl   = o_Cs + 1572864;           // 3,145,728 (scanA->scanC; Hin in-place)

    dim3 b256(256);
    // prep
    k_prepA<<<24, b256, 0, stream>>>(s2_Alog, s4_Alog, w + o_A2, w + o_A4);
    k_addgroups<<<2048, b256, 0, stream>>>(x, w + o_x13, w + o_x42);
    k_pool<<<512, b256, 0, stream>>>(x, w + o_gfp);
    k_conv1L<<<256, b256, 0, stream>>>(x, conv1_w, c1g, c1b, c1m, c1v, w + o_out1);
    k_conv3L<<<256, b256, 0, stream>>>(w + o_x13, conv3_w, w + o_out3);

    // ---- SS2D #1 (N=8, conv 3x3, input x[:,32:64]) ----
    {
        const int N = 8;
        k_s1<<<256, b256, 0, stream>>>(x, CCH * LL, 32, s2_inw, w + o_xiT, w + o_zT);
        k_s2<3><<<1024, b256, 0, stream>>>(w + o_xiT, s2_cw, s2_cb, w + o_xcT);
        k_s3<N><<<4096, b256, 0, stream>>>(w + o_xcT, s2_xpw, w + o_r01, w + o_Bs, w + o_Cs);
        k_scanA<N><<<2048, b256, 0, stream>>>(w + o_r01, w + o_Bs, w + o_xcT, w + o_A2,
                                              s2_dtw, s2_dtb, w + o_Pp, w + o_Hl);
        k_scanB<N><<<(16 * N * 64 + 255) / 256, b256, 0, stream>>>(w + o_Pp, w + o_Hl);
        k_scanC<N><<<2048, b256, 0, stream>>>(w + o_r01, w + o_Bs, w + o_Cs, w + o_xcT,
                                              w + o_A2, s2_dtw, s2_dtb, w + o_Hl, w + o_yrT);
        k_combine<<<512, b256, 0, stream>>>(w + o_yrT, w + o_xcT, w + o_zT, s2_D,
                                            s2_lng, s2_lnb, s2_outw, w + o_sbuf);
        k_gtail<<<512, b256, 0, stream>>>(w + o_sbuf, g2_pw, w + o_gfp, 32, -1,
                                          g2g, g2b, g2m, g2v, w + o_out2);
    }
    // ---- SS2D #2 (N=24, conv 7x7, input x42) ----
    {
        const int N = 24;
        k_s1<<<256, b256, 0, stream>>>(w + o_x42, 32 * LL, 0, s4_inw, w + o_xiT, w + o_zT);
        k_s2<7><<<1024, b256, 0, stream>>>(w + o_xiT, s4_cw, s4_cb, w + o_xcT);
        k_s3<N><<<4096, b256, 0, stream>>>(w + o_xcT, s4_xpw, w + o_r01, w + o_Bs, w + o_Cs);
        k_scanA<N><<<2048, b256, 0, stream>>>(w + o_r01, w + o_Bs, w + o_xcT, w + o_A4,
                                              s4_dtw, s4_dtb, w + o_Pp, w + o_Hl);
        k_scanB<N><<<(16 * N * 64 + 255) / 256, b256, 0, stream>>>(w + o_Pp, w + o_Hl);
        k_scanC<N><<<2048, b256, 0, stream>>>(w + o_r01, w + o_Bs, w + o_Cs, w + o_xcT,
                                              w + o_A4, s4_dtw, s4_dtb, w + o_Hl, w + o_yrT);
        k_combine<<<512, b256, 0, stream>>>(w + o_yrT, w + o_xcT, w + o_zT, s4_D,
                                            s4_lng, s4_lnb, s4_outw, w + o_sbuf);
        k_gtail<<<512, b256, 0, stream>>>(w + o_sbuf, g4_pw, w + o_gfp, 96, 32,
                                          g4g, g4b, g4m, g4v, w + o_out4);
    }

    // tail (o_S region free again: ybuf/sa/sap overlay it)
    k_gf<<<1, dim3(512), 0, stream>>>(w + o_gfp, gp_w, proj_w, w + o_gf, w + o_pgf);
    k_proj<<<512, b256, 0, stream>>>(x, w + o_out1, w + o_out2, w + o_out3, w + o_out4,
                                     proj_w, w + o_pgf, pjg, pjb, pjm, pjv, w + o_ybuf);
    k_pool<<<512, b256, 0, stream>>>(w + o_ybuf, w + o_ypool);
    k_ca<<<4, dim3(128), 0, stream>>>(w + o_ypool, ca_w1, ca_b1, ca_w2, ca_b2, w + o_ca);
    k_sa_part<<<2048, b256, 0, stream>>>(w + o_ybuf, sa_w, w + o_sap);
    k_sared<<<64, b256, 0, stream>>>(w + o_sap, w + o_sa);
    k_final<<<8192, b256, 0, stream>>>(w + o_ybuf, w + o_ca, w + o_sa, out);
}